// Round 8
// baseline (1698.246 us; speedup 1.0000x reference)
//
#include <hip/hip_runtime.h>
#include <hip/hip_bf16.h>
#include <stdint.h>

#define NB 8
#define NC 64
#define NN 4096
#define NK 16
#define NO 64
#define TILE 64
#define NSTEPS 64     // 64-col steps over the full 4096 cols
#define NKC 32        // candidates kept per row (bf16 top-32, rescored in fp32)

typedef __attribute__((ext_vector_type(8))) short bf16x8;
typedef __attribute__((ext_vector_type(4))) float f32x4;

// ---------------------------------------------------------------------------
// Kernel 1: per-point projections + squared norms + bf16 copy of x in [n][c].
// PQ[b][n][r], r in [0,192): 0..63 = x·(W1e-W2e)^T + b_edge, 64..127 = x·W2e^T,
// 128..191 = x·W2a^T   (Q1 and b_att cancel in the softmax over k)
// H[b][n][c] = bf16(x) row-major per point (MFMA operand layout).
// ---------------------------------------------------------------------------
__global__ __launch_bounds__(256) void proj_kernel(
    const float* __restrict__ x, const float* __restrict__ We,
    const float* __restrict__ be, const float* __restrict__ Wa,
    float* __restrict__ PQ, float* __restrict__ sq,
    unsigned short* __restrict__ H)
{
  __shared__ float xs[NC][TILE];
  __shared__ float wt[NC][192];
  const int bid = blockIdx.x;
  const int b   = bid >> 6;
  const int n0  = (bid & 63) * TILE;
  const int tid = threadIdx.x;

  const float4* xg4 = (const float4*)x;
  float4* xs4 = (float4*)xs;
  for (int i = tid; i < NC * TILE / 4; i += 256) {
    int c = i >> 4, p4 = i & 15;
    xs4[c * 16 + p4] = xg4[(b * NC + c) * (NN / 4) + (n0 >> 2) + p4];
  }
  for (int i = tid; i < 64 * NC; i += 256) {
    int o = i >> 6, c = i & 63;
    float w1 = We[o * 128 + c], w2 = We[o * 128 + 64 + c];
    wt[c][o]        = w1 - w2;
    wt[c][64 + o]   = w2;
    wt[c][128 + o]  = Wa[o * 128 + 64 + c];
  }
  __syncthreads();

  // ---- bf16 transpose-write: thread (p = tid&63, cg = tid>>6) writes 16 c ----
  {
    const int p = tid & 63, cg = tid >> 6;
    union { unsigned short u16[16]; uint4 v[2]; } hs;
    #pragma unroll
    for (int j = 0; j < 16; ++j) {
      float v = xs[cg * 16 + j][p];
      __hip_bfloat16 hh = __float2bfloat16(v);
      hs.u16[j] = *reinterpret_cast<unsigned short*>(&hh);
    }
    uint4* Hp = (uint4*)(H + ((size_t)(b * NN + n0 + p) * NC + cg * 16));
    Hp[0] = hs.v[0];
    Hp[1] = hs.v[1];
  }

  if (tid >= 192) {
    int p = tid - 192;
    float s = 0.f;
    #pragma unroll
    for (int c = 0; c < NC; ++c) { float v = xs[c][p]; s = fmaf(v, v, s); }
    sq[b * NN + n0 + p] = s;
  } else {
    const int r = tid;
    float wreg[NC];
    #pragma unroll
    for (int c = 0; c < NC; ++c) wreg[c] = wt[c][r];
    const float bias = (r < 64) ? be[r] : 0.f;
    for (int p = 0; p < TILE; p += 4) {
      float a0 = bias, a1 = bias, a2 = bias, a3 = bias;
      #pragma unroll
      for (int c = 0; c < NC; ++c) {
        float4 xv = *(const float4*)&xs[c][p];
        a0 = fmaf(wreg[c], xv.x, a0);
        a1 = fmaf(wreg[c], xv.y, a1);
        a2 = fmaf(wreg[c], xv.z, a2);
        a3 = fmaf(wreg[c], xv.w, a3);
      }
      int base = (b * NN + n0 + p) * 192 + r;
      PQ[base]           = a0;
      PQ[base + 192]     = a1;
      PQ[base + 2 * 192] = a2;
      PQ[base + 3 * 192] = a3;
    }
  }
}

// ---------------------------------------------------------------------------
// Kernel 2: bf16-MFMA pairwise scores + streaming top-32 candidates.
// Block = 64 rows x all 4096 cols (64 steps of 64). 256 threads / 4 waves;
// wave w owns rows w*16..w*16+15: 4 col-tiles x 2 K-halves = 8 mfma/step.
// Two-segment phases (R5-proven):
//   A: issue Hc stage loads(t+1); scan distT(t-1); mfma(t)
//   barrier; B: distT <- scores(t); Hc <- staged(t+1); barrier
// LDS: Hr 8K + Hc 8K (both XOR-swizzled bf16) + distT [64][68] 17K = 33.8 KB.
// Scores = sq[col] - 2*dot_bf16 (fp32 accum); scan = R7 machinery with NK=32.
// Rescore safety: true fp32-top-16 is inside bf16-top-32 with >10x margin.
// ---------------------------------------------------------------------------
__global__ __launch_bounds__(256, 3) void knn_kernel(
    const unsigned short* __restrict__ H, const float* __restrict__ sq,
    unsigned short* __restrict__ cand)
{
  __shared__ unsigned short Hr[64 * 64];   // 8 KB bf16, rows of 128 B, swizzled
  __shared__ unsigned short Hc[64 * 64];   // 8 KB
  __shared__ float distT[TILE][68];        // 17.4 KB (272 B rows, 16B-aligned)

  const int bid = blockIdx.x;
  const int b   = bid >> 6;
  const int rt  = bid & 63;
  const int r0  = rt * TILE;
  const int tid = threadIdx.x;
  const int w    = tid >> 6;
  const int lane = tid & 63;
  const int lm   = lane & 15;     // A-row / B-col / D-col within tile
  const int lk   = lane >> 4;     // k-group

  const int srow = tid >> 2;      // scan: row 0..63
  const int ssub = tid & 3;       // scan: 16-col group

  const unsigned short* Hb = H + (size_t)b * NN * NC;
  const float* sqg = sq + (size_t)b * NN;

  // ---- prologue: stage Hr (row tile) and Hc (col tile 0), swizzled ----
  const int rowS = tid >> 2, subS = tid & 3;
  {
    const int byt = rowS * 128 + subS * 32;
    const int swz = (rowS & 7) << 4;
    const uint4* srcR = (const uint4*)(Hb + (size_t)(r0 + rowS) * NC + subS * 16);
    *(uint4*)((char*)Hr + ((byt) ^ swz))      = srcR[0];
    *(uint4*)((char*)Hr + ((byt + 16) ^ swz)) = srcR[1];
    const uint4* srcC = (const uint4*)(Hb + (size_t)rowS * NC + subS * 16);
    *(uint4*)((char*)Hc + ((byt) ^ swz))      = srcC[0];
    *(uint4*)((char*)Hc + ((byt + 16) ^ swz)) = srcC[1];
  }
  __syncthreads();

  // ---- A-fragments: loop-invariant (row tile persistent) ----
  const int arow  = w * 16 + lm;
  const int aswz  = (arow & 7) << 4;
  const bf16x8 a0 = *(const bf16x8*)((const char*)Hr + ((arow * 128 + lk * 16) ^ aswz));
  const bf16x8 a1 = *(const bf16x8*)((const char*)Hr + ((arow * 128 + lk * 16 + 64) ^ aswz));

  float bv[NKC]; int bi[NKC];
  #pragma unroll
  for (int t = 0; t < NKC; ++t) { bv[t] = 3.0e38f; bi[t] = 0; }
  float rowGuard = 3.0e38f;

  for (int t = 0; t <= NSTEPS; ++t) {
    // ================= segment A: reads only =================
    uint4 st0, st1;
    const bool doStage = (t + 1 < NSTEPS);
    if (doStage) {
      const uint4* src = (const uint4*)(Hb + (size_t)((t + 1) * TILE + rowS) * NC + subS * 16);
      st0 = src[0]; st1 = src[1];
    }
    float sqv[4];
    if (t < NSTEPS) {
      #pragma unroll
      for (int ct = 0; ct < 4; ++ct) sqv[ct] = sqg[t * TILE + ct * 16 + lm];
    }

    // ---- scan distT (scores of step t-1), NK=32, proven machinery ----
    if (t > 0) {
      const int n1 = (t - 1) * TILE;
      float d[16];
      #pragma unroll
      for (int j4 = 0; j4 < 4; ++j4) {
        float4 t4 = *(const float4*)&distT[srow][ssub * 16 + j4 * 4];
        d[j4 * 4 + 0] = t4.x; d[j4 * 4 + 1] = t4.y;
        d[j4 * 4 + 2] = t4.z; d[j4 * 4 + 3] = t4.w;
      }
      float m = d[0]; int mi = 0;
      #pragma unroll
      for (int i = 1; i < 16; ++i) {
        bool c2 = d[i] < m; m = c2 ? d[i] : m; mi = c2 ? i : mi;
      }
      float guard = fminf(bv[NKC - 1], rowGuard);
      #pragma unroll 1
      for (int rnd = 0; rnd < 16; ++rnd) {
        bool ins = m < guard;
        if (!__any(ins)) break;
        float v  = ins ? m : 3.0e38f;
        int  vmi = ins ? mi : -1;
        if (v < bv[NKC - 1]) {
          bv[NKC - 1] = v; bi[NKC - 1] = n1 + ssub * 16 + vmi;
          #pragma unroll
          for (int q = NKC - 1; q > 0; --q) {
            if (bv[q] < bv[q - 1]) {
              float tv = bv[q]; bv[q] = bv[q - 1]; bv[q - 1] = tv;
              int   ti = bi[q]; bi[q] = bi[q - 1]; bi[q - 1] = ti;
            }
          }
        }
        #pragma unroll
        for (int i = 0; i < 16; ++i) d[i] = (i == vmi) ? 3.0e38f : d[i];
        m = d[0]; mi = 0;
        #pragma unroll
        for (int i = 1; i < 16; ++i) {
          bool c2 = d[i] < m; m = c2 ? d[i] : m; mi = c2 ? i : mi;
        }
        guard = fminf(bv[NKC - 1], rowGuard);
      }
      float g15 = bv[NKC - 1];
      g15 = fminf(g15, __shfl_xor(g15, 1));
      g15 = fminf(g15, __shfl_xor(g15, 2));
      rowGuard = g15;
    }

    if (t < NSTEPS) {
      // ---- MFMA: 4 col-tiles x K=64 (2 insts each) ----
      f32x4 acc[4];
      #pragma unroll
      for (int ct = 0; ct < 4; ++ct) acc[ct] = (f32x4){0.f, 0.f, 0.f, 0.f};
      #pragma unroll
      for (int ct = 0; ct < 4; ++ct) {
        const int brow = ct * 16 + lm;
        const int bswz = (brow & 7) << 4;
        bf16x8 b0 = *(const bf16x8*)((const char*)Hc + ((brow * 128 + lk * 16) ^ bswz));
        bf16x8 b1 = *(const bf16x8*)((const char*)Hc + ((brow * 128 + lk * 16 + 64) ^ bswz));
        acc[ct] = __builtin_amdgcn_mfma_f32_16x16x32_bf16(a0, b0, acc[ct], 0, 0, 0);
        acc[ct] = __builtin_amdgcn_mfma_f32_16x16x32_bf16(a1, b1, acc[ct], 0, 0, 0);
      }

      __syncthreads();   // barrier 1: scan reads of distT + mfma reads of Hc done

      // ================= segment B: writes only =================
      #pragma unroll
      for (int ct = 0; ct < 4; ++ct) {
        #pragma unroll
        for (int r = 0; r < 4; ++r) {
          distT[w * 16 + lk * 4 + r][ct * 16 + lm] = fmaf(-2.f, acc[ct][r], sqv[ct]);
        }
      }
      if (doStage) {
        const int byt = rowS * 128 + subS * 32;
        const int swz = (rowS & 7) << 4;
        *(uint4*)((char*)Hc + ((byt) ^ swz))      = st0;
        *(uint4*)((char*)Hc + ((byt + 16) ^ swz)) = st1;
      }
      __syncthreads();   // barrier 2: writes visible
    }
  }

  // ---- merge the 4 per-lane lists per row (two row-halves; reuse LDS) ----
  float* mv = (float*)distT;               // 32 rows * 4 lists * 32 = 4096 f32
  unsigned short* mi2 = Hr;                // 4096 u16 (idx < 4096)
  for (int half = 0; half < 2; ++half) {
    __syncthreads();
    const int lr = srow & 31;
    if ((srow >> 5) == half) {
      #pragma unroll
      for (int t2 = 0; t2 < NKC; ++t2) {
        mv [(lr * 4 + ssub) * NKC + t2] = bv[t2];
        mi2[(lr * 4 + ssub) * NKC + t2] = (unsigned short)bi[t2];
      }
    }
    __syncthreads();
    if ((srow >> 5) == half && ssub == 0) {
      for (int s2 = 1; s2 < 4; ++s2) {
        for (int t2 = 0; t2 < NKC; ++t2) {
          float v = mv[(lr * 4 + s2) * NKC + t2];
          if (v >= bv[NKC - 1]) break;     // lists sorted ascending
          bv[NKC - 1] = v; bi[NKC - 1] = (int)mi2[(lr * 4 + s2) * NKC + t2];
          #pragma unroll
          for (int q = NKC - 1; q > 0; --q) {
            if (bv[q] < bv[q - 1]) {
              float tv = bv[q]; bv[q] = bv[q - 1]; bv[q - 1] = tv;
              int   ti = bi[q]; bi[q] = bi[q - 1]; bi[q - 1] = ti;
            }
          }
        }
      }
      unsigned short* cp = cand + (size_t)(b * NN + r0 + srow) * NKC;
      #pragma unroll
      for (int t2 = 0; t2 < NKC; ++t2) cp[t2] = (unsigned short)bi[t2];
    }
  }
}

// ---------------------------------------------------------------------------
// Kernel 3: exact fp32 rescore of the 32 candidates -> top-16 indices.
// 4 threads per row (c-split 16 each), quad shfl-reduce, lane0 selects.
// Ranking key sq[j] - 2*dot is monotone-equal to the reference distance.
// ---------------------------------------------------------------------------
__global__ __launch_bounds__(256, 2) void rescore_kernel(
    const float* __restrict__ x, const float* __restrict__ sq,
    const unsigned short* __restrict__ cand, int* __restrict__ nn_idx)
{
  const int gid = blockIdx.x * 256 + threadIdx.x;
  const int row = gid >> 2;
  const int cq  = gid & 3;
  const int b = row >> 12, n = row & (NN - 1);
  const float* xb  = x + (size_t)b * NC * NN;
  const float* sqg = sq + (size_t)b * NN;

  int j[NKC];
  {
    const uint4* cp = (const uint4*)(cand + (size_t)row * NKC);
    #pragma unroll
    for (int v4 = 0; v4 < 4; ++v4) {
      uint4 u = cp[v4];
      j[v4 * 8 + 0] = (int)(u.x & 0xFFFF); j[v4 * 8 + 1] = (int)(u.x >> 16);
      j[v4 * 8 + 2] = (int)(u.y & 0xFFFF); j[v4 * 8 + 3] = (int)(u.y >> 16);
      j[v4 * 8 + 4] = (int)(u.z & 0xFFFF); j[v4 * 8 + 5] = (int)(u.z >> 16);
      j[v4 * 8 + 6] = (int)(u.w & 0xFFFF); j[v4 * 8 + 7] = (int)(u.w >> 16);
    }
  }
  float s[NKC];
  #pragma unroll
  for (int t = 0; t < NKC; ++t) s[t] = 0.f;
  for (int ci = 0; ci < 16; ++ci) {
    const int c = cq * 16 + ci;
    const float* xc = xb + (size_t)c * NN;
    const float xn = xc[n];
    #pragma unroll
    for (int t = 0; t < NKC; ++t) s[t] = fmaf(xn, xc[j[t]], s[t]);
  }
  #pragma unroll
  for (int t = 0; t < NKC; ++t) {
    s[t] += __shfl_xor(s[t], 1);
    s[t] += __shfl_xor(s[t], 2);
  }
  if (cq == 0) {
    float bvv[NK]; int bbi[NK];
    #pragma unroll
    for (int q = 0; q < NK; ++q) { bvv[q] = 3.0e38f; bbi[q] = 0; }
    #pragma unroll
    for (int t = 0; t < NKC; ++t) {
      float v = fmaf(-2.f, s[t], sqg[j[t]]);
      if (v < bvv[NK - 1]) {
        bvv[NK - 1] = v; bbi[NK - 1] = j[t];
        #pragma unroll
        for (int q = NK - 1; q > 0; --q) {
          if (bvv[q] < bvv[q - 1]) {
            float tv = bvv[q]; bvv[q] = bvv[q - 1]; bvv[q - 1] = tv;
            int   ti = bbi[q]; bbi[q] = bbi[q - 1]; bbi[q - 1] = ti;
          }
        }
      }
    }
    int* np = nn_idx + (size_t)row * NK;
    #pragma unroll
    for (int q = 0; q < NK; ++q) np[q] = bbi[q];
  }
}

// ---------------------------------------------------------------------------
// Kernel 4: gather neighbors' P2/Q2, softmax over k, weighted sum. (unchanged)
// ---------------------------------------------------------------------------
__global__ __launch_bounds__(256) void out_kernel(
    const float* __restrict__ PQ, const int* __restrict__ nn_idx,
    float* __restrict__ out)
{
  __shared__ float ot[TILE][TILE + 1];
  const int bid = blockIdx.x;
  const int b   = bid >> 6;
  const int n0  = (bid & 63) * TILE;
  const int tid = threadIdx.x;
  const int w = tid >> 6, o = tid & 63;

  for (int pi = 0; pi < 16; ++pi) {
    const int p = w * 16 + pi;
    const int n = n0 + p;
    const float* pqn = PQ + (b * NN + n) * 192;
    const float p1b  = pqn[o];
    const int* idxp  = nn_idx + (b * NN + n) * NK;
    float p2[NK], q2[NK];
    #pragma unroll
    for (int t = 0; t < NK; ++t) {
      int jn = idxp[t];
      const float* pqj = PQ + (b * NN + jn) * 192;
      p2[t] = pqj[64 + o];
      q2[t] = pqj[128 + o];
    }
    float m = q2[0];
    #pragma unroll
    for (int t = 1; t < NK; ++t) m = fmaxf(m, q2[t]);
    float s = 0.f, num = 0.f;
    #pragma unroll
    for (int t = 0; t < NK; ++t) {
      float e = __expf(q2[t] - m);
      s += e;
      num = fmaf(e, p1b + p2[t], num);
    }
    ot[p][o] = num / s;
  }
  __syncthreads();

  const int oo = tid >> 2, qq = tid & 3;
  float* og = out + (b * NO + oo) * NN + n0 + qq * 16;
  #pragma unroll
  for (int i = 0; i < 4; ++i) {
    float4 v;
    v.x = ot[qq * 16 + i * 4 + 0][oo];
    v.y = ot[qq * 16 + i * 4 + 1][oo];
    v.z = ot[qq * 16 + i * 4 + 2][oo];
    v.w = ot[qq * 16 + i * 4 + 3][oo];
    *(float4*)&og[i * 4] = v;
  }
}

// ---------------------------------------------------------------------------
extern "C" void kernel_launch(void* const* d_in, const int* in_sizes, int n_in,
                              void* d_out, int out_size, void* d_ws, size_t ws_size,
                              hipStream_t stream)
{
  const float* x  = (const float*)d_in[0];
  const float* We = (const float*)d_in[1];
  const float* be = (const float*)d_in[2];
  const float* Wa = (const float*)d_in[3];
  float* out = (float*)d_out;

  // workspace layout (total 33,685,504 B == proven-safe R1 footprint)
  char* ws = (char*)d_ws;
  size_t off = 0;
  float* sq = (float*)(ws + off);            off += (size_t)NB * NN * 4;            // 128 KB
  float* PQ = (float*)(ws + off);            off += (size_t)NB * NN * 192 * 4;      // 24 MB
  unsigned short* H    = (unsigned short*)(ws + off); off += (size_t)NB * NN * NC * 2;   // 4 MB
  unsigned short* cand = (unsigned short*)(ws + off); off += (size_t)NB * NN * NKC * 2;  // 2 MB
  int* nn = (int*)(ws + off);                                                       // 2 MB

  dim3 blk(256);
  proj_kernel<<<dim3(NB * (NN / TILE)), blk, 0, stream>>>(x, We, be, Wa, PQ, sq, H);
  knn_kernel<<<dim3(NB * (NN / TILE)), blk, 0, stream>>>(H, sq, cand);
  rescore_kernel<<<dim3(NB * NN * 4 / 256), blk, 0, stream>>>(x, sq, cand, nn);
  out_kernel<<<dim3(NB * (NN / TILE)), blk, 0, stream>>>(PQ, nn, out);
}

// Round 9
// 1031.761 us; speedup vs baseline: 1.6460x; 1.6460x over previous
//
#include <hip/hip_runtime.h>
#include <hip/hip_bf16.h>
#include <stdint.h>

#define NB 8
#define NC 64
#define NN 4096
#define NK 16
#define NO 64
#define TILE 64
#define NCHUNK 2
#define CHCOLS (NN / NCHUNK)     // 2048
#define NTILES (CHCOLS / TILE)   // 32
#define NKL 16                   // per-lane candidate list (exact per-class top-16)

typedef __attribute__((ext_vector_type(8))) short bf16x8;
typedef __attribute__((ext_vector_type(4))) float f32x4;

// ---------------------------------------------------------------------------
// Kernel 1: projections + squared norms + bf16 copy of x in [n][c]. (R8 proven)
// PQ[b][n][r]: 0..63 = x·(W1e-W2e)^T + b_edge, 64..127 = x·W2e^T, 128..191 = x·W2a^T
// ---------------------------------------------------------------------------
__global__ __launch_bounds__(256) void proj_kernel(
    const float* __restrict__ x, const float* __restrict__ We,
    const float* __restrict__ be, const float* __restrict__ Wa,
    float* __restrict__ PQ, float* __restrict__ sq,
    unsigned short* __restrict__ H)
{
  __shared__ float xs[NC][TILE];
  __shared__ float wt[NC][192];
  const int bid = blockIdx.x;
  const int b   = bid >> 6;
  const int n0  = (bid & 63) * TILE;
  const int tid = threadIdx.x;

  const float4* xg4 = (const float4*)x;
  float4* xs4 = (float4*)xs;
  for (int i = tid; i < NC * TILE / 4; i += 256) {
    int c = i >> 4, p4 = i & 15;
    xs4[c * 16 + p4] = xg4[(b * NC + c) * (NN / 4) + (n0 >> 2) + p4];
  }
  for (int i = tid; i < 64 * NC; i += 256) {
    int o = i >> 6, c = i & 63;
    float w1 = We[o * 128 + c], w2 = We[o * 128 + 64 + c];
    wt[c][o]        = w1 - w2;
    wt[c][64 + o]   = w2;
    wt[c][128 + o]  = Wa[o * 128 + 64 + c];
  }
  __syncthreads();

  {
    const int p = tid & 63, cg = tid >> 6;
    union { unsigned short u16[16]; uint4 v[2]; } hs;
    #pragma unroll
    for (int j = 0; j < 16; ++j) {
      float v = xs[cg * 16 + j][p];
      __hip_bfloat16 hh = __float2bfloat16(v);
      hs.u16[j] = *reinterpret_cast<unsigned short*>(&hh);
    }
    uint4* Hp = (uint4*)(H + ((size_t)(b * NN + n0 + p) * NC + cg * 16));
    Hp[0] = hs.v[0];
    Hp[1] = hs.v[1];
  }

  if (tid >= 192) {
    int p = tid - 192;
    float s = 0.f;
    #pragma unroll
    for (int c = 0; c < NC; ++c) { float v = xs[c][p]; s = fmaf(v, v, s); }
    sq[b * NN + n0 + p] = s;
  } else {
    const int r = tid;
    float wreg[NC];
    #pragma unroll
    for (int c = 0; c < NC; ++c) wreg[c] = wt[c][r];
    const float bias = (r < 64) ? be[r] : 0.f;
    for (int p = 0; p < TILE; p += 4) {
      float a0 = bias, a1 = bias, a2 = bias, a3 = bias;
      #pragma unroll
      for (int c = 0; c < NC; ++c) {
        float4 xv = *(const float4*)&xs[c][p];
        a0 = fmaf(wreg[c], xv.x, a0);
        a1 = fmaf(wreg[c], xv.y, a1);
        a2 = fmaf(wreg[c], xv.z, a2);
        a3 = fmaf(wreg[c], xv.w, a3);
      }
      int base = (b * NN + n0 + p) * 192 + r;
      PQ[base]           = a0;
      PQ[base + 192]     = a1;
      PQ[base + 2 * 192] = a2;
      PQ[base + 3 * 192] = a3;
    }
  }
}

// ---------------------------------------------------------------------------
// Kernel 2: swapped-operand bf16-MFMA scores, scan directly from accumulators.
// mfma(Hc_frag, Hr_frag) -> D[n][m]: lane holds 16 cols of ONE row (row=lane&15
// within wave-group, cols = ct*16 + lk*4 + reg). No distT, 1 barrier/step.
// Block: 4 waves x 16 rows = 64 rows, 2048-col chunk (32 steps).
// Per-lane EXACT top-16 of its mod-16 col class; epilogue merges 4 lanes -> 32.
// Grid 1024 = 4 blocks/CU exactly; LDS 24 KB.
// ---------------------------------------------------------------------------
__global__ __launch_bounds__(256, 4) void knn_kernel(
    const unsigned short* __restrict__ H, const float* __restrict__ sq,
    unsigned short* __restrict__ cand)
{
  __shared__ unsigned short Hc[2][64 * 64];   // 2 x 8 KB, swizzled 128B rows
  __shared__ unsigned short Hr[64 * 64];      // 8 KB

  const int bid = blockIdx.x;
  const int b   = bid >> 7;
  const int rt  = (bid >> 1) & 63;
  const int ch  = bid & 1;
  const int r0  = rt * TILE;
  const int c0  = ch * CHCOLS;
  const int tid = threadIdx.x;
  const int w    = tid >> 6;
  const int lane = tid & 63;
  const int lm   = lane & 15;
  const int lk   = lane >> 4;

  const unsigned short* Hb = H + (size_t)b * NN * NC;
  const float* sqg = sq + (size_t)b * NN;

  const int rowS = tid >> 2, subS = tid & 3;
  const int bytS = rowS * 128 + subS * 32;
  const int swzS = (rowS & 7) << 4;

  // ---- prologue: stage Hr (rows) and Hc[0] (col tile 0), XOR-swizzled ----
  {
    const uint4* srcR = (const uint4*)(Hb + (size_t)(r0 + rowS) * NC + subS * 16);
    *(uint4*)((char*)Hr + ((bytS)      ^ swzS)) = srcR[0];
    *(uint4*)((char*)Hr + ((bytS + 16) ^ swzS)) = srcR[1];
    const uint4* srcC = (const uint4*)(Hb + (size_t)(c0 + rowS) * NC + subS * 16);
    *(uint4*)((char*)Hc[0] + ((bytS)      ^ swzS)) = srcC[0];
    *(uint4*)((char*)Hc[0] + ((bytS + 16) ^ swzS)) = srcC[1];
  }
  __syncthreads();

  // ---- B-operand frags: OWN row (persistent, 8 VGPR-pairs) ----
  const int brow = w * 16 + lm;
  const int bswz = (brow & 7) << 4;
  const bf16x8 bf0 = *(const bf16x8*)((const char*)Hr + ((brow * 128 + lk * 16)      ^ bswz));
  const bf16x8 bf1 = *(const bf16x8*)((const char*)Hr + ((brow * 128 + lk * 16 + 64) ^ bswz));

  float bv[NKL]; int bi[NKL];
  #pragma unroll
  for (int t = 0; t < NKL; ++t) { bv[t] = 3.0e38f; bi[t] = 0; }

  for (int t = 0; t < NTILES; ++t) {
    const int cur = t & 1;
    // ---- issue next-tile staging loads early ----
    uint4 st0, st1;
    const bool doStage = (t + 1 < NTILES);
    if (doStage) {
      const uint4* src = (const uint4*)(Hb + (size_t)(c0 + (t + 1) * TILE + rowS) * NC + subS * 16);
      st0 = src[0]; st1 = src[1];
    }
    const int n1 = c0 + t * TILE;

    // ---- MFMA: A = col frags (from Hc), B = own-row frags ----
    f32x4 acc[4];
    #pragma unroll
    for (int ct = 0; ct < 4; ++ct) acc[ct] = (f32x4){0.f, 0.f, 0.f, 0.f};
    #pragma unroll
    for (int ct = 0; ct < 4; ++ct) {
      const int arow = ct * 16 + lm;
      const int aswz = (arow & 7) << 4;
      bf16x8 a0 = *(const bf16x8*)((const char*)Hc[cur] + ((arow * 128 + lk * 16)      ^ aswz));
      bf16x8 a1 = *(const bf16x8*)((const char*)Hc[cur] + ((arow * 128 + lk * 16 + 64) ^ aswz));
      acc[ct] = __builtin_amdgcn_mfma_f32_16x16x32_bf16(a0, bf0, acc[ct], 0, 0, 0);
      acc[ct] = __builtin_amdgcn_mfma_f32_16x16x32_bf16(a1, bf1, acc[ct], 0, 0, 0);
    }

    // ---- scores into registers: d[i], i = ct*4+r  <->  col n1+ct*16+lk*4+r ----
    float d[16];
    #pragma unroll
    for (int ct = 0; ct < 4; ++ct) {
      const float4 s4 = *(const float4*)&sqg[n1 + ct * 16 + lk * 4];
      d[ct * 4 + 0] = fmaf(-2.f, acc[ct][0], s4.x);
      d[ct * 4 + 1] = fmaf(-2.f, acc[ct][1], s4.y);
      d[ct * 4 + 2] = fmaf(-2.f, acc[ct][2], s4.z);
      d[ct * 4 + 3] = fmaf(-2.f, acc[ct][3], s4.w);
    }

    // ---- in-register top-16 scan (extract-min rounds, proven machinery) ----
    float m = d[0]; int mi = 0;
    #pragma unroll
    for (int i = 1; i < 16; ++i) {
      bool c2 = d[i] < m; m = c2 ? d[i] : m; mi = c2 ? i : mi;
    }
    #pragma unroll 1
    for (int rnd = 0; rnd < 16; ++rnd) {
      bool ins = m < bv[NKL - 1];
      if (!__any(ins)) break;
      float v  = ins ? m : 3.0e38f;
      int  vmi = ins ? mi : -1;
      if (v < bv[NKL - 1]) {
        bv[NKL - 1] = v;
        bi[NKL - 1] = n1 + ((vmi >> 2) << 4) + (lk << 2) + (vmi & 3);
        #pragma unroll
        for (int q = NKL - 1; q > 0; --q) {
          if (bv[q] < bv[q - 1]) {
            float tv = bv[q]; bv[q] = bv[q - 1]; bv[q - 1] = tv;
            int   ti = bi[q]; bi[q] = bi[q - 1]; bi[q - 1] = ti;
          }
        }
      }
      #pragma unroll
      for (int i = 0; i < 16; ++i) d[i] = (i == vmi) ? 3.0e38f : d[i];
      m = d[0]; mi = 0;
      #pragma unroll
      for (int i = 1; i < 16; ++i) {
        bool c2 = d[i] < m; m = c2 ? d[i] : m; mi = c2 ? i : mi;
      }
    }

    // ---- write staged tile into the OTHER buffer; single barrier ----
    if (doStage) {
      *(uint4*)((char*)Hc[cur ^ 1] + ((bytS)      ^ swzS)) = st0;
      *(uint4*)((char*)Hc[cur ^ 1] + ((bytS + 16) ^ swzS)) = st1;
    }
    __syncthreads();
  }

  // ---- epilogue: merge 4 sorted-16 lane lists -> top-32/row (2 half-passes) ----
  float* mv = (float*)&Hc[0][0];                 // 32 rows x 4 x 16 f32 = 8 KB
  unsigned short* mi2 = (unsigned short*)&Hc[1][0];  // 4 KB
  const int myrow = w * 16 + lm;                 // 0..63
  for (int half = 0; half < 2; ++half) {
    __syncthreads();
    if ((myrow >> 5) == half) {
      const int lr = myrow & 31;
      #pragma unroll
      for (int t = 0; t < NKL; ++t) {
        mv [(lr * 4 + lk) * NKL + t] = bv[t];
        mi2[(lr * 4 + lk) * NKL + t] = (unsigned short)bi[t];
      }
    }
    __syncthreads();
    if ((myrow >> 5) == half && lk == 0) {
      const int lr = myrow & 31;
      float cv[32]; int ci[32];
      #pragma unroll
      for (int q = 0; q < 32; ++q) { cv[q] = 3.0e38f; ci[q] = 0; }
      for (int s2 = 0; s2 < 4; ++s2) {
        for (int t = 0; t < NKL; ++t) {
          float v = mv[(lr * 4 + s2) * NKL + t];
          if (v >= cv[31]) break;       // lane lists sorted ascending
          cv[31] = v; ci[31] = (int)mi2[(lr * 4 + s2) * NKL + t];
          #pragma unroll
          for (int q = 31; q > 0; --q) {
            if (cv[q] < cv[q - 1]) {
              float tv = cv[q]; cv[q] = cv[q - 1]; cv[q - 1] = tv;
              int   ti = ci[q]; ci[q] = ci[q - 1]; ci[q - 1] = ti;
            }
          }
        }
      }
      unsigned short* cp = cand + ((size_t)(b * NN + r0 + myrow) * NCHUNK + ch) * 32;
      #pragma unroll
      for (int q = 0; q < 32; ++q) cp[q] = (unsigned short)ci[q];
    }
  }
}

// ---------------------------------------------------------------------------
// Kernel 3: exact fp32 rescore of the 64 concat candidates -> top-16.
// 8 lanes/row x 8 candidates each; selection per row from LDS.
// ---------------------------------------------------------------------------
__global__ __launch_bounds__(256) void rescore_kernel(
    const float* __restrict__ x, const float* __restrict__ sq,
    const unsigned short* __restrict__ cand, int* __restrict__ nn_idx)
{
  __shared__ float dv[32][64];
  __shared__ unsigned short di[32][64];
  const int tid  = threadIdx.x;
  const int rowL = tid >> 3;
  const int l8   = tid & 7;
  const int row  = blockIdx.x * 32 + rowL;
  const int b = row >> 12, n = row & (NN - 1);
  const float* xb  = x + (size_t)b * NC * NN;
  const float* sqg = sq + (size_t)b * NN;

  int j[8];
  {
    uint4 u = *(const uint4*)(cand + (size_t)row * 64 + l8 * 8);
    j[0] = (int)(u.x & 0xFFFF); j[1] = (int)(u.x >> 16);
    j[2] = (int)(u.y & 0xFFFF); j[3] = (int)(u.y >> 16);
    j[4] = (int)(u.z & 0xFFFF); j[5] = (int)(u.z >> 16);
    j[6] = (int)(u.w & 0xFFFF); j[7] = (int)(u.w >> 16);
  }
  float s[8];
  #pragma unroll
  for (int q = 0; q < 8; ++q) s[q] = 0.f;
  for (int c = 0; c < NC; ++c) {
    const float* xc = xb + (size_t)c * NN;
    const float xn = xc[n];
    #pragma unroll
    for (int q = 0; q < 8; ++q) s[q] = fmaf(xn, xc[j[q]], s[q]);
  }
  #pragma unroll
  for (int q = 0; q < 8; ++q) {
    dv[rowL][l8 * 8 + q] = fmaf(-2.f, s[q], sqg[j[q]]);
    di[rowL][l8 * 8 + q] = (unsigned short)j[q];
  }
  __syncthreads();
  if (l8 == 0) {
    float bvv[NK]; int bbi[NK];
    #pragma unroll
    for (int q = 0; q < NK; ++q) { bvv[q] = 3.0e38f; bbi[q] = 0; }
    for (int q = 0; q < 64; ++q) {
      float v = dv[rowL][q];
      if (v < bvv[NK - 1]) {
        bvv[NK - 1] = v; bbi[NK - 1] = (int)di[rowL][q];
        #pragma unroll
        for (int p = NK - 1; p > 0; --p) {
          if (bvv[p] < bvv[p - 1]) {
            float tv = bvv[p]; bvv[p] = bvv[p - 1]; bvv[p - 1] = tv;
            int   ti = bbi[p]; bbi[p] = bbi[p - 1]; bbi[p - 1] = ti;
          }
        }
      }
    }
    int* np = nn_idx + (size_t)row * NK;
    #pragma unroll
    for (int q = 0; q < NK; ++q) np[q] = bbi[q];
  }
}

// ---------------------------------------------------------------------------
// Kernel 4: gather neighbors' P2/Q2, softmax over k, weighted sum. (unchanged)
// ---------------------------------------------------------------------------
__global__ __launch_bounds__(256) void out_kernel(
    const float* __restrict__ PQ, const int* __restrict__ nn_idx,
    float* __restrict__ out)
{
  __shared__ float ot[TILE][TILE + 1];
  const int bid = blockIdx.x;
  const int b   = bid >> 6;
  const int n0  = (bid & 63) * TILE;
  const int tid = threadIdx.x;
  const int w = tid >> 6, o = tid & 63;

  for (int pi = 0; pi < 16; ++pi) {
    const int p = w * 16 + pi;
    const int n = n0 + p;
    const float* pqn = PQ + (b * NN + n) * 192;
    const float p1b  = pqn[o];
    const int* idxp  = nn_idx + (b * NN + n) * NK;
    float p2[NK], q2[NK];
    #pragma unroll
    for (int t = 0; t < NK; ++t) {
      int jn = idxp[t];
      const float* pqj = PQ + (b * NN + jn) * 192;
      p2[t] = pqj[64 + o];
      q2[t] = pqj[128 + o];
    }
    float m = q2[0];
    #pragma unroll
    for (int t = 1; t < NK; ++t) m = fmaxf(m, q2[t]);
    float s = 0.f, num = 0.f;
    #pragma unroll
    for (int t = 0; t < NK; ++t) {
      float e = __expf(q2[t] - m);
      s += e;
      num = fmaf(e, p1b + p2[t], num);
    }
    ot[p][o] = num / s;
  }
  __syncthreads();

  const int oo = tid >> 2, qq = tid & 3;
  float* og = out + (b * NO + oo) * NN + n0 + qq * 16;
  #pragma unroll
  for (int i = 0; i < 4; ++i) {
    float4 v;
    v.x = ot[qq * 16 + i * 4 + 0][oo];
    v.y = ot[qq * 16 + i * 4 + 1][oo];
    v.z = ot[qq * 16 + i * 4 + 2][oo];
    v.w = ot[qq * 16 + i * 4 + 3][oo];
    *(float4*)&og[i * 4] = v;
  }
}

// ---------------------------------------------------------------------------
extern "C" void kernel_launch(void* const* d_in, const int* in_sizes, int n_in,
                              void* d_out, int out_size, void* d_ws, size_t ws_size,
                              hipStream_t stream)
{
  const float* x  = (const float*)d_in[0];
  const float* We = (const float*)d_in[1];
  const float* be = (const float*)d_in[2];
  const float* Wa = (const float*)d_in[3];
  float* out = (float*)d_out;

  // workspace: 32.1 MB (proven envelope). nn aliases H (H dead after knn).
  char* ws = (char*)d_ws;
  size_t off = 0;
  float* sq = (float*)(ws + off);                     off += (size_t)NB * NN * 4;        // 128 KB
  float* PQ = (float*)(ws + off);                     off += (size_t)NB * NN * 192 * 4;  // 24 MB
  unsigned short* H = (unsigned short*)(ws + off);    off += (size_t)NB * NN * NC * 2;   // 4 MB
  unsigned short* cand = (unsigned short*)(ws + off);                                    // 4 MB
  int* nn = (int*)H;   // alias: H consumed by knn before rescore writes nn

  dim3 blk(256);
  proj_kernel<<<dim3(NB * (NN / TILE)), blk, 0, stream>>>(x, We, be, Wa, PQ, sq, H);
  knn_kernel<<<dim3(NB * (NN / TILE) * NCHUNK), blk, 0, stream>>>(H, sq, cand);
  rescore_kernel<<<dim3(NB * NN / 32), blk, 0, stream>>>(x, sq, cand, nn);
  out_kernel<<<dim3(NB * (NN / TILE)), blk, 0, stream>>>(PQ, nn, out);
}

// Round 10
// 493.715 us; speedup vs baseline: 3.4397x; 2.0898x over previous
//
#include <hip/hip_runtime.h>
#include <hip/hip_bf16.h>
#include <stdint.h>

#define NB 8
#define NC 64
#define NN 4096
#define NK 16
#define NO 64
#define TILE 64
#define NCHUNK 2
#define CHCOLS (NN / NCHUNK)     // 2048
#define NTILES (CHCOLS / TILE)   // 32
#define NKL 16                   // per-lane candidate list (guarded exact)
#define NKC 32                   // candidates per row handed to rescore (2 x 16)

typedef __attribute__((ext_vector_type(8))) short bf16x8;
typedef __attribute__((ext_vector_type(4))) float f32x4;

// ---------------------------------------------------------------------------
// Kernel 1: projections + squared norms + bf16 copy of x in [n][c]. (proven)
// PQ[b][n][r]: 0..63 = x·(W1e-W2e)^T + b_edge, 64..127 = x·W2e^T, 128..191 = x·W2a^T
// ---------------------------------------------------------------------------
__global__ __launch_bounds__(256) void proj_kernel(
    const float* __restrict__ x, const float* __restrict__ We,
    const float* __restrict__ be, const float* __restrict__ Wa,
    float* __restrict__ PQ, float* __restrict__ sq,
    unsigned short* __restrict__ H)
{
  __shared__ float xs[NC][TILE];
  __shared__ float wt[NC][192];
  const int bid = blockIdx.x;
  const int b   = bid >> 6;
  const int n0  = (bid & 63) * TILE;
  const int tid = threadIdx.x;

  const float4* xg4 = (const float4*)x;
  float4* xs4 = (float4*)xs;
  for (int i = tid; i < NC * TILE / 4; i += 256) {
    int c = i >> 4, p4 = i & 15;
    xs4[c * 16 + p4] = xg4[(b * NC + c) * (NN / 4) + (n0 >> 2) + p4];
  }
  for (int i = tid; i < 64 * NC; i += 256) {
    int o = i >> 6, c = i & 63;
    float w1 = We[o * 128 + c], w2 = We[o * 128 + 64 + c];
    wt[c][o]        = w1 - w2;
    wt[c][64 + o]   = w2;
    wt[c][128 + o]  = Wa[o * 128 + 64 + c];
  }
  __syncthreads();

  {
    const int p = tid & 63, cg = tid >> 6;
    union { unsigned short u16[16]; uint4 v[2]; } hs;
    #pragma unroll
    for (int j = 0; j < 16; ++j) {
      float v = xs[cg * 16 + j][p];
      __hip_bfloat16 hh = __float2bfloat16(v);
      hs.u16[j] = *reinterpret_cast<unsigned short*>(&hh);
    }
    uint4* Hp = (uint4*)(H + ((size_t)(b * NN + n0 + p) * NC + cg * 16));
    Hp[0] = hs.v[0];
    Hp[1] = hs.v[1];
  }

  if (tid >= 192) {
    int p = tid - 192;
    float s = 0.f;
    #pragma unroll
    for (int c = 0; c < NC; ++c) { float v = xs[c][p]; s = fmaf(v, v, s); }
    sq[b * NN + n0 + p] = s;
  } else {
    const int r = tid;
    float wreg[NC];
    #pragma unroll
    for (int c = 0; c < NC; ++c) wreg[c] = wt[c][r];
    const float bias = (r < 64) ? be[r] : 0.f;
    for (int p = 0; p < TILE; p += 4) {
      float a0 = bias, a1 = bias, a2 = bias, a3 = bias;
      #pragma unroll
      for (int c = 0; c < NC; ++c) {
        float4 xv = *(const float4*)&xs[c][p];
        a0 = fmaf(wreg[c], xv.x, a0);
        a1 = fmaf(wreg[c], xv.y, a1);
        a2 = fmaf(wreg[c], xv.z, a2);
        a3 = fmaf(wreg[c], xv.w, a3);
      }
      int base = (b * NN + n0 + p) * 192 + r;
      PQ[base]           = a0;
      PQ[base + 192]     = a1;
      PQ[base + 2 * 192] = a2;
      PQ[base + 3 * 192] = a3;
    }
  }
}

// ---------------------------------------------------------------------------
// Kernel 2: swapped-operand bf16-MFMA scores, scan in registers (R9 structure)
// + rowGuard pruning (shfl_xor 16/32 across the 4 lanes of a row)
// + no min-waves hint (avoid the 64-VGPR spill trap).
// Per-lane guarded list; union over 4 lanes >= exact bf16-chunk-top-16.
// ---------------------------------------------------------------------------
__global__ __launch_bounds__(256) void knn_kernel(
    const unsigned short* __restrict__ H, const float* __restrict__ sq,
    unsigned short* __restrict__ cand)
{
  __shared__ unsigned short Hc[2][64 * 64];   // 2 x 8 KB, swizzled 128B rows
  __shared__ unsigned short Hr[64 * 64];      // 8 KB

  const int bid = blockIdx.x;
  const int b   = bid >> 7;
  const int rt  = (bid >> 1) & 63;
  const int ch  = bid & 1;
  const int r0  = rt * TILE;
  const int c0  = ch * CHCOLS;
  const int tid = threadIdx.x;
  const int w    = tid >> 6;
  const int lane = tid & 63;
  const int lm   = lane & 15;
  const int lk   = lane >> 4;

  const unsigned short* Hb = H + (size_t)b * NN * NC;
  const float* sqg = sq + (size_t)b * NN;

  const int rowS = tid >> 2, subS = tid & 3;
  const int bytS = rowS * 128 + subS * 32;
  const int swzS = (rowS & 7) << 4;

  // ---- prologue: stage Hr (rows) and Hc[0] (col tile 0), XOR-swizzled ----
  {
    const uint4* srcR = (const uint4*)(Hb + (size_t)(r0 + rowS) * NC + subS * 16);
    *(uint4*)((char*)Hr + ((bytS)      ^ swzS)) = srcR[0];
    *(uint4*)((char*)Hr + ((bytS + 16) ^ swzS)) = srcR[1];
    const uint4* srcC = (const uint4*)(Hb + (size_t)(c0 + rowS) * NC + subS * 16);
    *(uint4*)((char*)Hc[0] + ((bytS)      ^ swzS)) = srcC[0];
    *(uint4*)((char*)Hc[0] + ((bytS + 16) ^ swzS)) = srcC[1];
  }
  __syncthreads();

  // ---- B-operand frags: OWN row (persistent) ----
  const int brow = w * 16 + lm;
  const int bswz = (brow & 7) << 4;
  const bf16x8 bf0 = *(const bf16x8*)((const char*)Hr + ((brow * 128 + lk * 16)      ^ bswz));
  const bf16x8 bf1 = *(const bf16x8*)((const char*)Hr + ((brow * 128 + lk * 16 + 64) ^ bswz));

  float bv[NKL]; int bi[NKL];
  #pragma unroll
  for (int t = 0; t < NKL; ++t) { bv[t] = 3.0e38f; bi[t] = 0; }
  float rowGuard = 3.0e38f;

  for (int t = 0; t < NTILES; ++t) {
    const int cur = t & 1;
    uint4 st0, st1;
    const bool doStage = (t + 1 < NTILES);
    if (doStage) {
      const uint4* src = (const uint4*)(Hb + (size_t)(c0 + (t + 1) * TILE + rowS) * NC + subS * 16);
      st0 = src[0]; st1 = src[1];
    }
    const int n1 = c0 + t * TILE;

    // ---- MFMA: A = col frags (from Hc), B = own-row frags ----
    f32x4 acc[4];
    #pragma unroll
    for (int ct = 0; ct < 4; ++ct) acc[ct] = (f32x4){0.f, 0.f, 0.f, 0.f};
    #pragma unroll
    for (int ct = 0; ct < 4; ++ct) {
      const int arow = ct * 16 + lm;
      const int aswz = (arow & 7) << 4;
      bf16x8 a0 = *(const bf16x8*)((const char*)Hc[cur] + ((arow * 128 + lk * 16)      ^ aswz));
      bf16x8 a1 = *(const bf16x8*)((const char*)Hc[cur] + ((arow * 128 + lk * 16 + 64) ^ aswz));
      acc[ct] = __builtin_amdgcn_mfma_f32_16x16x32_bf16(a0, bf0, acc[ct], 0, 0, 0);
      acc[ct] = __builtin_amdgcn_mfma_f32_16x16x32_bf16(a1, bf1, acc[ct], 0, 0, 0);
    }

    // ---- scores: d[i], i = ct*4+r  <->  col n1 + ct*16 + lk*4 + r ----
    float d[16];
    #pragma unroll
    for (int ct = 0; ct < 4; ++ct) {
      const float4 s4 = *(const float4*)&sqg[n1 + ct * 16 + lk * 4];
      d[ct * 4 + 0] = fmaf(-2.f, acc[ct][0], s4.x);
      d[ct * 4 + 1] = fmaf(-2.f, acc[ct][1], s4.y);
      d[ct * 4 + 2] = fmaf(-2.f, acc[ct][2], s4.z);
      d[ct * 4 + 3] = fmaf(-2.f, acc[ct][3], s4.w);
    }

    // ---- guarded in-register scan (extract-min rounds) ----
    float m = d[0]; int mi = 0;
    #pragma unroll
    for (int i = 1; i < 16; ++i) {
      bool c2 = d[i] < m; m = c2 ? d[i] : m; mi = c2 ? i : mi;
    }
    float guard = fminf(bv[NKL - 1], rowGuard);
    #pragma unroll 1
    for (int rnd = 0; rnd < 16; ++rnd) {
      bool ins = m < guard;
      if (!__any(ins)) break;
      float v  = ins ? m : 3.0e38f;
      int  vmi = ins ? mi : -1;
      if (v < bv[NKL - 1]) {
        bv[NKL - 1] = v;
        bi[NKL - 1] = n1 + ((vmi >> 2) << 4) + (lk << 2) + (vmi & 3);
        #pragma unroll
        for (int q = NKL - 1; q > 0; --q) {
          if (bv[q] < bv[q - 1]) {
            float tv = bv[q]; bv[q] = bv[q - 1]; bv[q - 1] = tv;
            int   ti = bi[q]; bi[q] = bi[q - 1]; bi[q - 1] = ti;
          }
        }
      }
      #pragma unroll
      for (int i = 0; i < 16; ++i) d[i] = (i == vmi) ? 3.0e38f : d[i];
      m = d[0]; mi = 0;
      #pragma unroll
      for (int i = 1; i < 16; ++i) {
        bool c2 = d[i] < m; m = c2 ? d[i] : m; mi = c2 ? i : mi;
      }
      guard = fminf(bv[NKL - 1], rowGuard);
    }
    // refresh the row's collective-16th guard (lanes lm, lm^16, lm^32, lm^48)
    float g15 = bv[NKL - 1];
    g15 = fminf(g15, __shfl_xor(g15, 16));
    g15 = fminf(g15, __shfl_xor(g15, 32));
    rowGuard = g15;

    // ---- write staged tile into the OTHER buffer; single barrier ----
    if (doStage) {
      *(uint4*)((char*)Hc[cur ^ 1] + ((bytS)      ^ swzS)) = st0;
      *(uint4*)((char*)Hc[cur ^ 1] + ((bytS + 16) ^ swzS)) = st1;
    }
    __syncthreads();
  }

  // ---- epilogue: merge 4 guarded lane lists -> exact chunk top-16/row ----
  float* mv = (float*)&Hc[0][0];                 // 64 rows x 4 x 16 f32 = 16 KB
  unsigned short* mi2 = Hr;                      // 8 KB
  const int myrow = w * 16 + lm;                 // 0..63
  __syncthreads();
  #pragma unroll
  for (int t = 0; t < NKL; ++t) {
    mv [(myrow * 4 + lk) * NKL + t] = bv[t];
    mi2[(myrow * 4 + lk) * NKL + t] = (unsigned short)bi[t];
  }
  __syncthreads();
  if (lk == 0) {
    for (int s2 = 1; s2 < 4; ++s2) {
      for (int t = 0; t < NKL; ++t) {
        float v = mv[(myrow * 4 + s2) * NKL + t];
        if (v >= bv[NKL - 1]) break;   // lane lists sorted ascending
        bv[NKL - 1] = v; bi[NKL - 1] = (int)mi2[(myrow * 4 + s2) * NKL + t];
        #pragma unroll
        for (int q = NKL - 1; q > 0; --q) {
          if (bv[q] < bv[q - 1]) {
            float tv = bv[q]; bv[q] = bv[q - 1]; bv[q - 1] = tv;
            int   ti = bi[q]; bi[q] = bi[q - 1]; bi[q - 1] = ti;
          }
        }
      }
    }
    unsigned short* cp = cand + (size_t)(b * NN + r0 + myrow) * NKC + ch * NKL;
    #pragma unroll
    for (int t = 0; t < NKL; ++t) cp[t] = (unsigned short)bi[t];
  }
}

// ---------------------------------------------------------------------------
// Kernel 3: exact fp32 rescore of the 32 candidates -> top-16 indices.
// (R8-proven) 4 threads/row (c-split 16), quad shfl-reduce, lane0 selects.
// ---------------------------------------------------------------------------
__global__ __launch_bounds__(256) void rescore_kernel(
    const float* __restrict__ x, const float* __restrict__ sq,
    const unsigned short* __restrict__ cand, int* __restrict__ nn_idx)
{
  const int gid = blockIdx.x * 256 + threadIdx.x;
  const int row = gid >> 2;
  const int cq  = gid & 3;
  const int b = row >> 12, n = row & (NN - 1);
  const float* xb  = x + (size_t)b * NC * NN;
  const float* sqg = sq + (size_t)b * NN;

  int j[NKC];
  {
    const uint4* cp = (const uint4*)(cand + (size_t)row * NKC);
    #pragma unroll
    for (int v4 = 0; v4 < 4; ++v4) {
      uint4 u = cp[v4];
      j[v4 * 8 + 0] = (int)(u.x & 0xFFFF); j[v4 * 8 + 1] = (int)(u.x >> 16);
      j[v4 * 8 + 2] = (int)(u.y & 0xFFFF); j[v4 * 8 + 3] = (int)(u.y >> 16);
      j[v4 * 8 + 4] = (int)(u.z & 0xFFFF); j[v4 * 8 + 5] = (int)(u.z >> 16);
      j[v4 * 8 + 6] = (int)(u.w & 0xFFFF); j[v4 * 8 + 7] = (int)(u.w >> 16);
    }
  }
  float s[NKC];
  #pragma unroll
  for (int t = 0; t < NKC; ++t) s[t] = 0.f;
  for (int ci = 0; ci < 16; ++ci) {
    const int c = cq * 16 + ci;
    const float* xc = xb + (size_t)c * NN;
    const float xn = xc[n];
    #pragma unroll
    for (int t = 0; t < NKC; ++t) s[t] = fmaf(xn, xc[j[t]], s[t]);
  }
  #pragma unroll
  for (int t = 0; t < NKC; ++t) {
    s[t] += __shfl_xor(s[t], 1);
    s[t] += __shfl_xor(s[t], 2);
  }
  if (cq == 0) {
    float bvv[NK]; int bbi[NK];
    #pragma unroll
    for (int q = 0; q < NK; ++q) { bvv[q] = 3.0e38f; bbi[q] = 0; }
    #pragma unroll
    for (int t = 0; t < NKC; ++t) {
      float v = fmaf(-2.f, s[t], sqg[j[t]]);
      if (v < bvv[NK - 1]) {
        bvv[NK - 1] = v; bbi[NK - 1] = j[t];
        #pragma unroll
        for (int q = NK - 1; q > 0; --q) {
          if (bvv[q] < bvv[q - 1]) {
            float tv = bvv[q]; bvv[q] = bvv[q - 1]; bvv[q - 1] = tv;
            int   ti = bbi[q]; bbi[q] = bbi[q - 1]; bbi[q - 1] = ti;
          }
        }
      }
    }
    int* np = nn_idx + (size_t)row * NK;
    #pragma unroll
    for (int q = 0; q < NK; ++q) np[q] = bbi[q];
  }
}

// ---------------------------------------------------------------------------
// Kernel 4: gather neighbors' P2/Q2, softmax over k, weighted sum. (unchanged)
// ---------------------------------------------------------------------------
__global__ __launch_bounds__(256) void out_kernel(
    const float* __restrict__ PQ, const int* __restrict__ nn_idx,
    float* __restrict__ out)
{
  __shared__ float ot[TILE][TILE + 1];
  const int bid = blockIdx.x;
  const int b   = bid >> 6;
  const int n0  = (bid & 63) * TILE;
  const int tid = threadIdx.x;
  const int w = tid >> 6, o = tid & 63;

  for (int pi = 0; pi < 16; ++pi) {
    const int p = w * 16 + pi;
    const int n = n0 + p;
    const float* pqn = PQ + (b * NN + n) * 192;
    const float p1b  = pqn[o];
    const int* idxp  = nn_idx + (b * NN + n) * NK;
    float p2[NK], q2[NK];
    #pragma unroll
    for (int t = 0; t < NK; ++t) {
      int jn = idxp[t];
      const float* pqj = PQ + (b * NN + jn) * 192;
      p2[t] = pqj[64 + o];
      q2[t] = pqj[128 + o];
    }
    float m = q2[0];
    #pragma unroll
    for (int t = 1; t < NK; ++t) m = fmaxf(m, q2[t]);
    float s = 0.f, num = 0.f;
    #pragma unroll
    for (int t = 0; t < NK; ++t) {
      float e = __expf(q2[t] - m);
      s += e;
      num = fmaf(e, p1b + p2[t], num);
    }
    ot[p][o] = num / s;
  }
  __syncthreads();

  const int oo = tid >> 2, qq = tid & 3;
  float* og = out + (b * NO + oo) * NN + n0 + qq * 16;
  #pragma unroll
  for (int i = 0; i < 4; ++i) {
    float4 v;
    v.x = ot[qq * 16 + i * 4 + 0][oo];
    v.y = ot[qq * 16 + i * 4 + 1][oo];
    v.z = ot[qq * 16 + i * 4 + 2][oo];
    v.w = ot[qq * 16 + i * 4 + 3][oo];
    *(float4*)&og[i * 4] = v;
  }
}

// ---------------------------------------------------------------------------
extern "C" void kernel_launch(void* const* d_in, const int* in_sizes, int n_in,
                              void* d_out, int out_size, void* d_ws, size_t ws_size,
                              hipStream_t stream)
{
  const float* x  = (const float*)d_in[0];
  const float* We = (const float*)d_in[1];
  const float* be = (const float*)d_in[2];
  const float* Wa = (const float*)d_in[3];
  float* out = (float*)d_out;

  // workspace: proven envelope. nn aliases H (H dead after knn).
  char* ws = (char*)d_ws;
  size_t off = 0;
  float* sq = (float*)(ws + off);                     off += (size_t)NB * NN * 4;        // 128 KB
  float* PQ = (float*)(ws + off);                     off += (size_t)NB * NN * 192 * 4;  // 24 MB
  unsigned short* H = (unsigned short*)(ws + off);    off += (size_t)NB * NN * NC * 2;   // 4 MB
  unsigned short* cand = (unsigned short*)(ws + off);                                    // 2 MB
  int* nn = (int*)H;   // alias: H consumed by knn before rescore writes nn

  dim3 blk(256);
  proj_kernel<<<dim3(NB * (NN / TILE)), blk, 0, stream>>>(x, We, be, Wa, PQ, sq, H);
  knn_kernel<<<dim3(NB * (NN / TILE) * NCHUNK), blk, 0, stream>>>(H, sq, cand);
  rescore_kernel<<<dim3(NB * NN * 4 / 256), blk, 0, stream>>>(x, sq, cand, nn);
  out_kernel<<<dim3(NB * (NN / TILE)), blk, 0, stream>>>(PQ, nn, out);
}

// Round 11
// 292.858 us; speedup vs baseline: 5.7989x; 1.6859x over previous
//
#include <hip/hip_runtime.h>
#include <hip/hip_bf16.h>
#include <stdint.h>

#define NB 8
#define NC 64
#define NN 4096
#define NK 16
#define NO 64
#define TILE 64
#define NCHUNK 2
#define CHCOLS (NN / NCHUNK)     // 2048
#define NTILES (CHCOLS / TILE)   // 32
#define NKL 16                   // per-lane guarded candidate list
#define NKC 32                   // candidates per row for rescore (2 x 16)
#define PQS 160                  // PQ row stride in floats (P1b 64 | P2 64 | Q2 bf16 x64)

typedef __attribute__((ext_vector_type(8))) short bf16x8;
typedef __attribute__((ext_vector_type(4))) float f32x4;

__device__ __forceinline__ unsigned umin32(unsigned a, unsigned b) { return a < b ? a : b; }
__device__ __forceinline__ unsigned shflx(unsigned v, int m) {
  return (unsigned)__shfl_xor((int)v, m);
}
// order-preserving fp32 -> uint map
__device__ __forceinline__ unsigned fmap(float x) {
  unsigned u = __float_as_uint(x);
  return u ^ ((unsigned)((int)u >> 31) | 0x80000000u);
}

// convert 16 fp32 -> 16 bf16 packed into two uint4
__device__ __forceinline__ void cvt16bf(const float4 st[4], uint4& lo, uint4& hi) {
  union { float4 v[4]; float f[16]; } in;
  in.v[0] = st[0]; in.v[1] = st[1]; in.v[2] = st[2]; in.v[3] = st[3];
  union { unsigned short h[16]; uint4 v[2]; } out;
  #pragma unroll
  for (int i = 0; i < 16; ++i) {
    __hip_bfloat16 hh = __float2bfloat16(in.f[i]);
    out.h[i] = *reinterpret_cast<unsigned short*>(&hh);
  }
  lo = out.v[0]; hi = out.v[1];
}

// ---------------------------------------------------------------------------
// Kernel 1: projections + squared norms + fp32 transpose XT[b][n][c].
// PQ[b][n][*]: 0..63 = x·(W1e-W2e)^T + b_edge (fp32), 64..127 = x·W2e^T (fp32),
// byte 512..639 = x·W2a^T as 64 bf16.  (Q1, b_att cancel in softmax over k.)
// ---------------------------------------------------------------------------
__global__ __launch_bounds__(256) void proj_kernel(
    const float* __restrict__ x, const float* __restrict__ We,
    const float* __restrict__ be, const float* __restrict__ Wa,
    float* __restrict__ PQ, float* __restrict__ sq,
    float* __restrict__ XT)
{
  __shared__ float xs[NC][TILE];
  __shared__ float wt[NC][192];
  const int bid = blockIdx.x;
  const int b   = bid >> 6;
  const int n0  = (bid & 63) * TILE;
  const int tid = threadIdx.x;

  const float4* xg4 = (const float4*)x;
  float4* xs4 = (float4*)xs;
  for (int i = tid; i < NC * TILE / 4; i += 256) {
    int c = i >> 4, p4 = i & 15;
    xs4[c * 16 + p4] = xg4[(b * NC + c) * (NN / 4) + (n0 >> 2) + p4];
  }
  for (int i = tid; i < 64 * NC; i += 256) {
    int o = i >> 6, c = i & 63;
    float w1 = We[o * 128 + c], w2 = We[o * 128 + 64 + c];
    wt[c][o]        = w1 - w2;
    wt[c][64 + o]   = w2;
    wt[c][128 + o]  = Wa[o * 128 + 64 + c];
  }
  __syncthreads();

  // ---- fp32 transpose-write: thread (p, cg) writes 16 channels of point p ----
  {
    const int p = tid & 63, cg = tid >> 6;
    float4 v4[4];
    #pragma unroll
    for (int g = 0; g < 4; ++g) {
      v4[g].x = xs[cg * 16 + g * 4 + 0][p];
      v4[g].y = xs[cg * 16 + g * 4 + 1][p];
      v4[g].z = xs[cg * 16 + g * 4 + 2][p];
      v4[g].w = xs[cg * 16 + g * 4 + 3][p];
    }
    float4* Xp = (float4*)(XT + ((size_t)(b * NN + n0 + p) * NC + cg * 16));
    Xp[0] = v4[0]; Xp[1] = v4[1]; Xp[2] = v4[2]; Xp[3] = v4[3];
  }

  if (tid >= 192) {
    int p = tid - 192;
    float s = 0.f;
    #pragma unroll
    for (int c = 0; c < NC; ++c) { float v = xs[c][p]; s = fmaf(v, v, s); }
    sq[b * NN + n0 + p] = s;
  } else {
    const int r = tid;
    float wreg[NC];
    #pragma unroll
    for (int c = 0; c < NC; ++c) wreg[c] = wt[c][r];
    const float bias = (r < 64) ? be[r] : 0.f;
    for (int p = 0; p < TILE; p += 4) {
      float a0 = bias, a1 = bias, a2 = bias, a3 = bias;
      #pragma unroll
      for (int c = 0; c < NC; ++c) {
        float4 xv = *(const float4*)&xs[c][p];
        a0 = fmaf(wreg[c], xv.x, a0);
        a1 = fmaf(wreg[c], xv.y, a1);
        a2 = fmaf(wreg[c], xv.z, a2);
        a3 = fmaf(wreg[c], xv.w, a3);
      }
      if (r < 128) {
        size_t base = (size_t)(b * NN + n0 + p) * PQS + r;
        PQ[base]           = a0;
        PQ[base + PQS]     = a1;
        PQ[base + 2 * PQS] = a2;
        PQ[base + 3 * PQS] = a3;
      } else {
        const int o = r - 128;
        unsigned short* qb = (unsigned short*)((char*)PQ + (size_t)(b * NN + n0 + p) * (PQS * 4) + 512) + o;
        const size_t stride = PQS * 2;   // in ushorts
        __hip_bfloat16 h0 = __float2bfloat16(a0);
        __hip_bfloat16 h1 = __float2bfloat16(a1);
        __hip_bfloat16 h2 = __float2bfloat16(a2);
        __hip_bfloat16 h3 = __float2bfloat16(a3);
        qb[0]          = *reinterpret_cast<unsigned short*>(&h0);
        qb[stride]     = *reinterpret_cast<unsigned short*>(&h1);
        qb[2 * stride] = *reinterpret_cast<unsigned short*>(&h2);
        qb[3 * stride] = *reinterpret_cast<unsigned short*>(&h3);
      }
    }
  }
}

// ---------------------------------------------------------------------------
// Kernel 2: swapped-operand bf16-MFMA scores + packed-uint guarded scan.
// Entry = (fmap(score) & 0xFFFFF800) | chunk-local col (11 bits): one reg,
// strict total order (col bits unique per row). Per-round rowGuard refresh.
// bf16 operands converted from XT during staging (no H buffer).
// ---------------------------------------------------------------------------
__global__ __launch_bounds__(256) void knn_kernel(
    const float* __restrict__ XT, const float* __restrict__ sq,
    unsigned short* __restrict__ cand)
{
  __shared__ unsigned short Hc[2][64 * 64];   // 2 x 8 KB, swizzled 128B rows
  __shared__ unsigned short Hr[64 * 64];      // 8 KB

  const int bid = blockIdx.x;
  const int b   = bid >> 7;
  const int rt  = (bid >> 1) & 63;
  const int ch  = bid & 1;
  const int r0  = rt * TILE;
  const int c0  = ch * CHCOLS;
  const int tid = threadIdx.x;
  const int w    = tid >> 6;
  const int lane = tid & 63;
  const int lm   = lane & 15;
  const int lk   = lane >> 4;

  const float* Xb  = XT + (size_t)b * NN * NC;
  const float* sqg = sq + (size_t)b * NN;

  const int rowS = tid >> 2, subS = tid & 3;
  const int bytS = rowS * 128 + subS * 32;
  const int swzS = (rowS & 7) << 4;

  // ---- prologue: stage Hr (rows) and Hc[0] (col tile 0): XT->bf16, swizzled ----
  {
    float4 st[4]; uint4 lo, hi;
    const float4* srcR = (const float4*)(Xb + (size_t)(r0 + rowS) * NC + subS * 16);
    st[0]=srcR[0]; st[1]=srcR[1]; st[2]=srcR[2]; st[3]=srcR[3];
    cvt16bf(st, lo, hi);
    *(uint4*)((char*)Hr + ((bytS)      ^ swzS)) = lo;
    *(uint4*)((char*)Hr + ((bytS + 16) ^ swzS)) = hi;
    const float4* srcC = (const float4*)(Xb + (size_t)(c0 + rowS) * NC + subS * 16);
    st[0]=srcC[0]; st[1]=srcC[1]; st[2]=srcC[2]; st[3]=srcC[3];
    cvt16bf(st, lo, hi);
    *(uint4*)((char*)Hc[0] + ((bytS)      ^ swzS)) = lo;
    *(uint4*)((char*)Hc[0] + ((bytS + 16) ^ swzS)) = hi;
  }
  __syncthreads();

  // ---- B-operand frags: OWN row (persistent) ----
  const int brow = w * 16 + lm;
  const int bswz = (brow & 7) << 4;
  const bf16x8 bf0 = *(const bf16x8*)((const char*)Hr + ((brow * 128 + lk * 16)      ^ bswz));
  const bf16x8 bf1 = *(const bf16x8*)((const char*)Hr + ((brow * 128 + lk * 16 + 64) ^ bswz));

  unsigned bv[NKL];
  #pragma unroll
  for (int t = 0; t < NKL; ++t) bv[t] = 0xFFFFFFFFu;
  unsigned rowGuard = 0xFFFFFFFFu;

  for (int t = 0; t < NTILES; ++t) {
    const int cur = t & 1;
    float4 st[4];
    const bool doStage = (t + 1 < NTILES);
    if (doStage) {
      const float4* src = (const float4*)(Xb + (size_t)(c0 + (t + 1) * TILE + rowS) * NC + subS * 16);
      st[0]=src[0]; st[1]=src[1]; st[2]=src[2]; st[3]=src[3];
    }
    const int n1 = c0 + t * TILE;

    // ---- MFMA: A = col frags (from Hc), B = own-row frags ----
    f32x4 acc[4];
    #pragma unroll
    for (int ct = 0; ct < 4; ++ct) acc[ct] = (f32x4){0.f, 0.f, 0.f, 0.f};
    #pragma unroll
    for (int ct = 0; ct < 4; ++ct) {
      const int arow = ct * 16 + lm;
      const int aswz = (arow & 7) << 4;
      bf16x8 a0 = *(const bf16x8*)((const char*)Hc[cur] + ((arow * 128 + lk * 16)      ^ aswz));
      bf16x8 a1 = *(const bf16x8*)((const char*)Hc[cur] + ((arow * 128 + lk * 16 + 64) ^ aswz));
      acc[ct] = __builtin_amdgcn_mfma_f32_16x16x32_bf16(a0, bf0, acc[ct], 0, 0, 0);
      acc[ct] = __builtin_amdgcn_mfma_f32_16x16x32_bf16(a1, bf1, acc[ct], 0, 0, 0);
    }

    // ---- packed scores: (fmap(d) & ~0x7FF) | chunk-local col ----
    unsigned d[16];
    #pragma unroll
    for (int ct = 0; ct < 4; ++ct) {
      const float4 s4 = *(const float4*)&sqg[n1 + ct * 16 + lk * 4];
      const int cbase = (t << 6) + (ct << 4) + (lk << 2);
      d[ct*4+0] = (fmap(fmaf(-2.f, acc[ct][0], s4.x)) & 0xFFFFF800u) | (unsigned)(cbase + 0);
      d[ct*4+1] = (fmap(fmaf(-2.f, acc[ct][1], s4.y)) & 0xFFFFF800u) | (unsigned)(cbase + 1);
      d[ct*4+2] = (fmap(fmaf(-2.f, acc[ct][2], s4.z)) & 0xFFFFF800u) | (unsigned)(cbase + 2);
      d[ct*4+3] = (fmap(fmaf(-2.f, acc[ct][3], s4.w)) & 0xFFFFF800u) | (unsigned)(cbase + 3);
    }

    // ---- guarded extract-min rounds on packed entries ----
    unsigned m = d[0];
    #pragma unroll
    for (int i = 1; i < 16; ++i) m = umin32(m, d[i]);
    unsigned guard = umin32(bv[NKL - 1], rowGuard);
    #pragma unroll 1
    for (int rnd = 0; rnd < 16; ++rnd) {
      bool ins = m < guard;
      if (!__any(ins)) break;
      unsigned x  = ins ? m : 0xFFFFFFFFu;
      const unsigned xv = x;
      #pragma unroll
      for (int i = 0; i < NKL; ++i) {
        unsigned lo = umin32(bv[i], x);
        x = bv[i] < x ? x : bv[i];   // max
        bv[i] = lo;
      }
      #pragma unroll
      for (int i = 0; i < 16; ++i) d[i] = (d[i] == xv) ? 0xFFFFFFFFu : d[i];
      m = d[0];
      #pragma unroll
      for (int i = 1; i < 16; ++i) m = umin32(m, d[i]);
      // refresh row guard (lanes lm, lm^16, lm^32, lm^48 hold this row)
      unsigned g15 = bv[NKL - 1];
      g15 = umin32(g15, shflx(g15, 16));
      g15 = umin32(g15, shflx(g15, 32));
      rowGuard = g15;
      guard = rowGuard;
    }

    // ---- write staged tile (bf16) into the OTHER buffer; single barrier ----
    if (doStage) {
      uint4 lo, hi;
      cvt16bf(st, lo, hi);
      *(uint4*)((char*)Hc[cur ^ 1] + ((bytS)      ^ swzS)) = lo;
      *(uint4*)((char*)Hc[cur ^ 1] + ((bytS + 16) ^ swzS)) = hi;
    }
    __syncthreads();
  }

  // ---- epilogue: merge 4 lane lists -> exact packed-top-16 per row ----
  unsigned* mv = (unsigned*)&Hc[0][0];           // 64 rows x 4 x 16 u32 = 16 KB
  const int myrow = w * 16 + lm;
  __syncthreads();
  #pragma unroll
  for (int t = 0; t < NKL; ++t) mv[(myrow * 4 + lk) * NKL + t] = bv[t];
  __syncthreads();
  if (lk == 0) {
    for (int s2 = 1; s2 < 4; ++s2) {
      for (int t = 0; t < NKL; ++t) {
        unsigned v = mv[(myrow * 4 + s2) * NKL + t];
        if (v >= bv[NKL - 1]) break;   // lane lists sorted ascending
        unsigned x = v;
        #pragma unroll
        for (int q = 0; q < NKL; ++q) {
          unsigned lo = umin32(bv[q], x);
          x = bv[q] < x ? x : bv[q];
          bv[q] = lo;
        }
      }
    }
    unsigned short* cp = cand + (size_t)(b * NN + r0 + myrow) * NKC + ch * NKL;
    #pragma unroll
    for (int t = 0; t < NKL; ++t)
      cp[t] = (unsigned short)((bv[t] & 0x7FFu) + c0);
  }
}

// ---------------------------------------------------------------------------
// Kernel 3: exact fp32 rescore, one lane per (row, candidate), XT layout.
// Block = 8 rows (4 waves x 2 rows); coalesced float4 candidate loads.
// nn (int16/row -> 64B) overlays cand (32 u16/row -> 64B): block-local RAW.
// ---------------------------------------------------------------------------
__global__ __launch_bounds__(256) void rescore_kernel(
    const float* __restrict__ XT, const float* __restrict__ sq,
    unsigned short* __restrict__ cand, int* __restrict__ nn_idx)
{
  __shared__ float dv[8][NKC];
  __shared__ unsigned short di[8][NKC];
  const int tid  = threadIdx.x;
  const int w    = tid >> 6;
  const int lane = tid & 63;
  const int rowL = w * 2 + (lane >> 5);      // 0..7
  const int q    = lane & 31;
  const int row  = blockIdx.x * 8 + rowL;
  const int b = row >> 12, n = row & (NN - 1);
  const float* xt  = XT + (size_t)b * NN * NC;
  const float* sqg = sq + (size_t)b * NN;

  const int j = (int)cand[(size_t)row * NKC + q];
  const float4* cj = (const float4*)(xt + (size_t)j * NC);
  const float4* cn = (const float4*)(xt + (size_t)n * NC);
  float s = 0.f;
  #pragma unroll
  for (int i = 0; i < 16; ++i) {
    float4 a = cn[i], bb = cj[i];
    s = fmaf(a.x, bb.x, s);
    s = fmaf(a.y, bb.y, s);
    s = fmaf(a.z, bb.z, s);
    s = fmaf(a.w, bb.w, s);
  }
  dv[rowL][q] = fmaf(-2.f, s, sqg[j]);
  di[rowL][q] = (unsigned short)j;
  __syncthreads();

  if (tid < 8) {
    const int row2 = blockIdx.x * 8 + tid;
    float bvv[NK]; int bbi[NK];
    #pragma unroll
    for (int p = 0; p < NK; ++p) { bvv[p] = 3.0e38f; bbi[p] = 0; }
    for (int t = 0; t < NKC; ++t) {
      float v = dv[tid][t];
      if (v < bvv[NK - 1]) {
        bvv[NK - 1] = v; bbi[NK - 1] = (int)di[tid][t];
        #pragma unroll
        for (int p = NK - 1; p > 0; --p) {
          if (bvv[p] < bvv[p - 1]) {
            float tv = bvv[p]; bvv[p] = bvv[p - 1]; bvv[p - 1] = tv;
            int   ti = bbi[p]; bbi[p] = bbi[p - 1]; bbi[p - 1] = ti;
          }
        }
      }
    }
    int* np = nn_idx + (size_t)row2 * NK;
    #pragma unroll
    for (int p = 0; p < NK; ++p) np[p] = bbi[p];
  }
}

// ---------------------------------------------------------------------------
// Kernel 4: gather neighbors' P2/Q2(bf16), softmax over k, weighted sum.
// ---------------------------------------------------------------------------
__global__ __launch_bounds__(256) void out_kernel(
    const float* __restrict__ PQ, const int* __restrict__ nn_idx,
    float* __restrict__ out)
{
  __shared__ float ot[TILE][TILE + 1];
  const int bid = blockIdx.x;
  const int b   = bid >> 6;
  const int n0  = (bid & 63) * TILE;
  const int tid = threadIdx.x;
  const int w = tid >> 6, o = tid & 63;

  for (int pi = 0; pi < 16; ++pi) {
    const int p = w * 16 + pi;
    const int n = n0 + p;
    const float* pqn = PQ + (size_t)(b * NN + n) * PQS;
    const float p1b  = pqn[o];
    const int* idxp  = nn_idx + (size_t)(b * NN + n) * NK;
    float p2[NK], q2[NK];
    #pragma unroll
    for (int t = 0; t < NK; ++t) {
      int jn = idxp[t];
      const float* pqj = PQ + (size_t)(b * NN + jn) * PQS;
      p2[t] = pqj[64 + o];
      unsigned short qh = ((const unsigned short*)(pqj + 128))[o];
      q2[t] = __bfloat162float(*reinterpret_cast<__hip_bfloat16*>(&qh));
    }
    float m = q2[0];
    #pragma unroll
    for (int t = 1; t < NK; ++t) m = fmaxf(m, q2[t]);
    float s = 0.f, num = 0.f;
    #pragma unroll
    for (int t = 0; t < NK; ++t) {
      float e = __expf(q2[t] - m);
      s += e;
      num = fmaf(e, p1b + p2[t], num);
    }
    ot[p][o] = num / s;
  }
  __syncthreads();

  const int oo = tid >> 2, qq = tid & 3;
  float* og = out + (size_t)(b * NO + oo) * NN + n0 + qq * 16;
  #pragma unroll
  for (int i = 0; i < 4; ++i) {
    float4 v;
    v.x = ot[qq * 16 + i * 4 + 0][oo];
    v.y = ot[qq * 16 + i * 4 + 1][oo];
    v.z = ot[qq * 16 + i * 4 + 2][oo];
    v.w = ot[qq * 16 + i * 4 + 3][oo];
    *(float4*)&og[i * 4] = v;
  }
}

// ---------------------------------------------------------------------------
extern "C" void kernel_launch(void* const* d_in, const int* in_sizes, int n_in,
                              void* d_out, int out_size, void* d_ws, size_t ws_size,
                              hipStream_t stream)
{
  const float* x  = (const float*)d_in[0];
  const float* We = (const float*)d_in[1];
  const float* be = (const float*)d_in[2];
  const float* Wa = (const float*)d_in[3];
  float* out = (float*)d_out;

  // workspace: 31.59 MB (< proven 33.69 MB envelope)
  char* ws = (char*)d_ws;
  size_t off = 0;
  float* sq = (float*)(ws + off);                  off += (size_t)NB * NN * 4;          // 128 KB
  float* PQ = (float*)(ws + off);                  off += (size_t)NB * NN * PQS * 4;    // 20 MB
  float* XT = (float*)(ws + off);                  off += (size_t)NB * NN * NC * 4;     // 8 MB
  unsigned short* cand = (unsigned short*)(ws + off);                                   // 2 MB
  int* nn = (int*)cand;   // exact per-row 64B overlay; written after reads (block-local)

  dim3 blk(256);
  proj_kernel<<<dim3(NB * (NN / TILE)), blk, 0, stream>>>(x, We, be, Wa, PQ, sq, XT);
  knn_kernel<<<dim3(NB * (NN / TILE) * NCHUNK), blk, 0, stream>>>(XT, sq, cand);
  rescore_kernel<<<dim3(NB * NN / 8), blk, 0, stream>>>(XT, sq, cand, nn);
  out_kernel<<<dim3(NB * (NN / TILE)), blk, 0, stream>>>(PQ, nn, out);
}

// Round 12
// 284.163 us; speedup vs baseline: 5.9763x; 1.0306x over previous
//
#include <hip/hip_runtime.h>
#include <hip/hip_bf16.h>
#include <stdint.h>

#define NB 8
#define NC 64
#define NN 4096
#define NK 16
#define NO 64
#define TILE 64
#define NCHUNK 2
#define CHCOLS (NN / NCHUNK)     // 2048
#define NTILES (CHCOLS / TILE)   // 32
#define NKL 16                   // per-lane guarded candidate list
#define NKC 32                   // candidates per row for rescore (2 x 16)

typedef __attribute__((ext_vector_type(8))) short bf16x8;
typedef __attribute__((ext_vector_type(4))) float f32x4;

__device__ __forceinline__ unsigned umin32(unsigned a, unsigned b) { return a < b ? a : b; }
__device__ __forceinline__ unsigned shflx(unsigned v, int m) {
  return (unsigned)__shfl_xor((int)v, m);
}
// order-preserving fp32 -> uint map
__device__ __forceinline__ unsigned fmap(float x) {
  unsigned u = __float_as_uint(x);
  return u ^ ((unsigned)((int)u >> 31) | 0x80000000u);
}
__device__ __forceinline__ float bf2f(unsigned short h) {
  return __bfloat162float(*reinterpret_cast<__hip_bfloat16*>(&h));
}
__device__ __forceinline__ unsigned short f2bfu(float v) {
  __hip_bfloat16 hh = __float2bfloat16(v);
  return *reinterpret_cast<unsigned short*>(&hh);
}

// ---------------------------------------------------------------------------
// Kernel 1: projections + norms + fp32 transpose XT[b][n][c] + bf16 H[b][n][c].
// PQb[b][n][r] (bf16): 0..63 = x·(W1e-W2e)^T + b_edge, 64..127 = x·W2e^T,
// 128..191 = x·W2a^T.  (Q1, b_att cancel in the softmax over k.)
// ---------------------------------------------------------------------------
__global__ __launch_bounds__(256) void proj_kernel(
    const float* __restrict__ x, const float* __restrict__ We,
    const float* __restrict__ be, const float* __restrict__ Wa,
    unsigned short* __restrict__ PQb, float* __restrict__ sq,
    float* __restrict__ XT, unsigned short* __restrict__ H)
{
  __shared__ float xs[NC][TILE];
  __shared__ float wt[NC][192];
  const int bid = blockIdx.x;
  const int b   = bid >> 6;
  const int n0  = (bid & 63) * TILE;
  const int tid = threadIdx.x;

  const float4* xg4 = (const float4*)x;
  float4* xs4 = (float4*)xs;
  for (int i = tid; i < NC * TILE / 4; i += 256) {
    int c = i >> 4, p4 = i & 15;
    xs4[c * 16 + p4] = xg4[(b * NC + c) * (NN / 4) + (n0 >> 2) + p4];
  }
  for (int i = tid; i < 64 * NC; i += 256) {
    int o = i >> 6, c = i & 63;
    float w1 = We[o * 128 + c], w2 = We[o * 128 + 64 + c];
    wt[c][o]        = w1 - w2;
    wt[c][64 + o]   = w2;
    wt[c][128 + o]  = Wa[o * 128 + 64 + c];
  }
  __syncthreads();

  // ---- transpose-writes: thread (p, cg) emits 16 channels (fp32 + bf16) ----
  {
    const int p = tid & 63, cg = tid >> 6;
    union { float4 v4[4]; float f[16]; } vv;
    #pragma unroll
    for (int g = 0; g < 4; ++g) {
      vv.v4[g].x = xs[cg * 16 + g * 4 + 0][p];
      vv.v4[g].y = xs[cg * 16 + g * 4 + 1][p];
      vv.v4[g].z = xs[cg * 16 + g * 4 + 2][p];
      vv.v4[g].w = xs[cg * 16 + g * 4 + 3][p];
    }
    float4* Xp = (float4*)(XT + ((size_t)(b * NN + n0 + p) * NC + cg * 16));
    Xp[0] = vv.v4[0]; Xp[1] = vv.v4[1]; Xp[2] = vv.v4[2]; Xp[3] = vv.v4[3];
    union { unsigned short h[16]; uint4 u[2]; } hs;
    #pragma unroll
    for (int i = 0; i < 16; ++i) hs.h[i] = f2bfu(vv.f[i]);
    uint4* Hp = (uint4*)(H + ((size_t)(b * NN + n0 + p) * NC + cg * 16));
    Hp[0] = hs.u[0]; Hp[1] = hs.u[1];
  }

  if (tid >= 192) {
    int p = tid - 192;
    float s = 0.f;
    #pragma unroll
    for (int c = 0; c < NC; ++c) { float v = xs[c][p]; s = fmaf(v, v, s); }
    sq[b * NN + n0 + p] = s;
  } else {
    const int r = tid;
    float wreg[NC];
    #pragma unroll
    for (int c = 0; c < NC; ++c) wreg[c] = wt[c][r];
    const float bias = (r < 64) ? be[r] : 0.f;
    for (int p = 0; p < TILE; p += 4) {
      float a0 = bias, a1 = bias, a2 = bias, a3 = bias;
      #pragma unroll
      for (int c = 0; c < NC; ++c) {
        float4 xv = *(const float4*)&xs[c][p];
        a0 = fmaf(wreg[c], xv.x, a0);
        a1 = fmaf(wreg[c], xv.y, a1);
        a2 = fmaf(wreg[c], xv.z, a2);
        a3 = fmaf(wreg[c], xv.w, a3);
      }
      size_t base = (size_t)(b * NN + n0 + p) * 192 + r;
      PQb[base]           = f2bfu(a0);
      PQb[base + 192]     = f2bfu(a1);
      PQb[base + 2*192]   = f2bfu(a2);
      PQb[base + 3*192]   = f2bfu(a3);
    }
  }
}

// ---------------------------------------------------------------------------
// Kernel 2: swapped-operand bf16-MFMA scores + LAZY-packed guarded scan.
// Scores stay fp32; pack to (fmap&~0x7FF)|col only in tiles where the wave's
// float min might beat the guard (exact skip test). R10-proven uint4 staging.
// ---------------------------------------------------------------------------
__global__ __launch_bounds__(256) void knn_kernel(
    const unsigned short* __restrict__ H, const float* __restrict__ sq,
    unsigned short* __restrict__ cand)
{
  __shared__ unsigned short Hc[2][64 * 64];   // 2 x 8 KB, swizzled 128B rows
  __shared__ unsigned short Hr[64 * 64];      // 8 KB

  const int bid = blockIdx.x;
  const int b   = bid >> 7;
  const int rt  = (bid >> 1) & 63;
  const int ch  = bid & 1;
  const int r0  = rt * TILE;
  const int c0  = ch * CHCOLS;
  const int tid = threadIdx.x;
  const int w    = tid >> 6;
  const int lane = tid & 63;
  const int lm   = lane & 15;
  const int lk   = lane >> 4;

  const unsigned short* Hb = H + (size_t)b * NN * NC;
  const float* sqg = sq + (size_t)b * NN;

  const int rowS = tid >> 2, subS = tid & 3;
  const int bytS = rowS * 128 + subS * 32;
  const int swzS = (rowS & 7) << 4;

  // ---- prologue: stage Hr (rows) and Hc[0] (col tile 0), XOR-swizzled ----
  {
    const uint4* srcR = (const uint4*)(Hb + (size_t)(r0 + rowS) * NC + subS * 16);
    *(uint4*)((char*)Hr + ((bytS)      ^ swzS)) = srcR[0];
    *(uint4*)((char*)Hr + ((bytS + 16) ^ swzS)) = srcR[1];
    const uint4* srcC = (const uint4*)(Hb + (size_t)(c0 + rowS) * NC + subS * 16);
    *(uint4*)((char*)Hc[0] + ((bytS)      ^ swzS)) = srcC[0];
    *(uint4*)((char*)Hc[0] + ((bytS + 16) ^ swzS)) = srcC[1];
  }
  __syncthreads();

  // ---- B-operand frags: OWN row (persistent) ----
  const int brow = w * 16 + lm;
  const int bswz = (brow & 7) << 4;
  const bf16x8 bf0 = *(const bf16x8*)((const char*)Hr + ((brow * 128 + lk * 16)      ^ bswz));
  const bf16x8 bf1 = *(const bf16x8*)((const char*)Hr + ((brow * 128 + lk * 16 + 64) ^ bswz));

  unsigned bv[NKL];
  #pragma unroll
  for (int t = 0; t < NKL; ++t) bv[t] = 0xFFFFFFFFu;
  unsigned rowGuard = 0xFFFFFFFFu;

  for (int t = 0; t < NTILES; ++t) {
    const int cur = t & 1;
    uint4 st0, st1;
    const bool doStage = (t + 1 < NTILES);
    if (doStage) {
      const uint4* src = (const uint4*)(Hb + (size_t)(c0 + (t + 1) * TILE + rowS) * NC + subS * 16);
      st0 = src[0]; st1 = src[1];
    }
    const int n1 = c0 + t * TILE;

    // ---- MFMA: A = col frags (from Hc), B = own-row frags ----
    f32x4 acc[4];
    #pragma unroll
    for (int ct = 0; ct < 4; ++ct) acc[ct] = (f32x4){0.f, 0.f, 0.f, 0.f};
    #pragma unroll
    for (int ct = 0; ct < 4; ++ct) {
      const int arow = ct * 16 + lm;
      const int aswz = (arow & 7) << 4;
      bf16x8 a0 = *(const bf16x8*)((const char*)Hc[cur] + ((arow * 128 + lk * 16)      ^ aswz));
      bf16x8 a1 = *(const bf16x8*)((const char*)Hc[cur] + ((arow * 128 + lk * 16 + 64) ^ aswz));
      acc[ct] = __builtin_amdgcn_mfma_f32_16x16x32_bf16(a0, bf0, acc[ct], 0, 0, 0);
      acc[ct] = __builtin_amdgcn_mfma_f32_16x16x32_bf16(a1, bf1, acc[ct], 0, 0, 0);
    }

    // ---- float scores (free from accumulators) + float min-tree ----
    float dd[16];
    #pragma unroll
    for (int ct = 0; ct < 4; ++ct) {
      const float4 s4 = *(const float4*)&sqg[n1 + ct * 16 + lk * 4];
      dd[ct*4+0] = fmaf(-2.f, acc[ct][0], s4.x);
      dd[ct*4+1] = fmaf(-2.f, acc[ct][1], s4.y);
      dd[ct*4+2] = fmaf(-2.f, acc[ct][2], s4.z);
      dd[ct*4+3] = fmaf(-2.f, acc[ct][3], s4.w);
    }
    float fm = dd[0];
    #pragma unroll
    for (int i = 1; i < 16; ++i) fm = fminf(fm, dd[i]);

    // ---- exact lazy skip: packed(any d) >= (fmap(fm)&~0x7FF); skip if that
    //      lower bound already fails the guard ----
    unsigned guard = umin32(bv[NKL - 1], rowGuard);
    const unsigned t1 = fmap(fm) & 0xFFFFF800u;
    if (__any(t1 < guard)) {
      // pack all 16: (fmap & ~0x7FF) | chunk-local col
      unsigned pd[16];
      #pragma unroll
      for (int ct = 0; ct < 4; ++ct) {
        const int cbase = (t << 6) + (ct << 4) + (lk << 2);
        pd[ct*4+0] = (fmap(dd[ct*4+0]) & 0xFFFFF800u) | (unsigned)(cbase + 0);
        pd[ct*4+1] = (fmap(dd[ct*4+1]) & 0xFFFFF800u) | (unsigned)(cbase + 1);
        pd[ct*4+2] = (fmap(dd[ct*4+2]) & 0xFFFFF800u) | (unsigned)(cbase + 2);
        pd[ct*4+3] = (fmap(dd[ct*4+3]) & 0xFFFFF800u) | (unsigned)(cbase + 3);
      }
      unsigned pm = pd[0];
      #pragma unroll
      for (int i = 1; i < 16; ++i) pm = umin32(pm, pd[i]);

      #pragma unroll 1
      for (int rnd = 0; rnd < 16; ++rnd) {
        bool ins = pm < guard;
        if (!__any(ins)) break;
        unsigned x = ins ? pm : 0xFFFFFFFFu;
        const unsigned xv = x;
        #pragma unroll
        for (int i = 0; i < NKL; ++i) {
          unsigned lo = umin32(bv[i], x);
          x = bv[i] < x ? x : bv[i];   // max
          bv[i] = lo;
        }
        #pragma unroll
        for (int i = 0; i < 16; ++i) pd[i] = (pd[i] == xv) ? 0xFFFFFFFFu : pd[i];
        pm = pd[0];
        #pragma unroll
        for (int i = 1; i < 16; ++i) pm = umin32(pm, pd[i]);
        // refresh row guard (lanes lm, lm^16, lm^32, lm^48 hold this row)
        unsigned g15 = bv[NKL - 1];
        g15 = umin32(g15, shflx(g15, 16));
        g15 = umin32(g15, shflx(g15, 32));
        rowGuard = g15;
        guard = rowGuard;
      }
    }

    // ---- write staged tile into the OTHER buffer; single barrier ----
    if (doStage) {
      *(uint4*)((char*)Hc[cur ^ 1] + ((bytS)      ^ swzS)) = st0;
      *(uint4*)((char*)Hc[cur ^ 1] + ((bytS + 16) ^ swzS)) = st1;
    }
    __syncthreads();
  }

  // ---- epilogue: merge 4 lane lists -> exact packed-top-16 per row ----
  unsigned* mv = (unsigned*)&Hc[0][0];           // 64 rows x 4 x 16 u32 = 16 KB
  const int myrow = w * 16 + lm;
  __syncthreads();
  #pragma unroll
  for (int t = 0; t < NKL; ++t) mv[(myrow * 4 + lk) * NKL + t] = bv[t];
  __syncthreads();
  if (lk == 0) {
    for (int s2 = 1; s2 < 4; ++s2) {
      for (int t = 0; t < NKL; ++t) {
        unsigned v = mv[(myrow * 4 + s2) * NKL + t];
        if (v >= bv[NKL - 1]) break;   // lane lists sorted ascending
        unsigned x = v;
        #pragma unroll
        for (int q = 0; q < NKL; ++q) {
          unsigned lo = umin32(bv[q], x);
          x = bv[q] < x ? x : bv[q];
          bv[q] = lo;
        }
      }
    }
    unsigned short* cp = cand + (size_t)(b * NN + r0 + myrow) * NKC + ch * NKL;
    #pragma unroll
    for (int t = 0; t < NKL; ++t)
      cp[t] = (unsigned short)((bv[t] & 0x7FFu) + c0);
  }
}

// ---------------------------------------------------------------------------
// Kernel 3: exact fp32 rescore, one lane per (row, candidate), XT layout.
// (R11-proven) nn overlays cand: exact 64B/row overlay, block-local RAW.
// ---------------------------------------------------------------------------
__global__ __launch_bounds__(256) void rescore_kernel(
    const float* __restrict__ XT, const float* __restrict__ sq,
    unsigned short* __restrict__ cand, int* __restrict__ nn_idx)
{
  __shared__ float dv[8][NKC];
  __shared__ unsigned short di[8][NKC];
  const int tid  = threadIdx.x;
  const int w    = tid >> 6;
  const int lane = tid & 63;
  const int rowL = w * 2 + (lane >> 5);      // 0..7
  const int q    = lane & 31;
  const int row  = blockIdx.x * 8 + rowL;
  const int b = row >> 12, n = row & (NN - 1);
  const float* xt  = XT + (size_t)b * NN * NC;
  const float* sqg = sq + (size_t)b * NN;

  const int j = (int)cand[(size_t)row * NKC + q];
  const float4* cj = (const float4*)(xt + (size_t)j * NC);
  const float4* cn = (const float4*)(xt + (size_t)n * NC);
  float s = 0.f;
  #pragma unroll
  for (int i = 0; i < 16; ++i) {
    float4 a = cn[i], bb = cj[i];
    s = fmaf(a.x, bb.x, s);
    s = fmaf(a.y, bb.y, s);
    s = fmaf(a.z, bb.z, s);
    s = fmaf(a.w, bb.w, s);
  }
  dv[rowL][q] = fmaf(-2.f, s, sqg[j]);
  di[rowL][q] = (unsigned short)j;
  __syncthreads();

  if (tid < 8) {
    const int row2 = blockIdx.x * 8 + tid;
    float bvv[NK]; int bbi[NK];
    #pragma unroll
    for (int p = 0; p < NK; ++p) { bvv[p] = 3.0e38f; bbi[p] = 0; }
    for (int t = 0; t < NKC; ++t) {
      float v = dv[tid][t];
      if (v < bvv[NK - 1]) {
        bvv[NK - 1] = v; bbi[NK - 1] = (int)di[tid][t];
        #pragma unroll
        for (int p = NK - 1; p > 0; --p) {
          if (bvv[p] < bvv[p - 1]) {
            float tv = bvv[p]; bvv[p] = bvv[p - 1]; bvv[p - 1] = tv;
            int   ti = bbi[p]; bbi[p] = bbi[p - 1]; bbi[p - 1] = ti;
          }
        }
      }
    }
    int* np = nn_idx + (size_t)row2 * NK;
    #pragma unroll
    for (int p = 0; p < NK; ++p) np[p] = bbi[p];
  }
}

// ---------------------------------------------------------------------------
// Kernel 4: gather neighbors' P2/Q2 (bf16), softmax over k, weighted sum.
// ---------------------------------------------------------------------------
__global__ __launch_bounds__(256) void out_kernel(
    const unsigned short* __restrict__ PQb, const int* __restrict__ nn_idx,
    float* __restrict__ out)
{
  __shared__ float ot[TILE][TILE + 1];
  const int bid = blockIdx.x;
  const int b   = bid >> 6;
  const int n0  = (bid & 63) * TILE;
  const int tid = threadIdx.x;
  const int w = tid >> 6, o = tid & 63;

  for (int pi = 0; pi < 16; ++pi) {
    const int p = w * 16 + pi;
    const int n = n0 + p;
    const unsigned short* pqn = PQb + (size_t)(b * NN + n) * 192;
    const float p1b  = bf2f(pqn[o]);
    const int* idxp  = nn_idx + (size_t)(b * NN + n) * NK;
    float p2[NK], q2[NK];
    #pragma unroll
    for (int t = 0; t < NK; ++t) {
      int jn = idxp[t];
      const unsigned short* pqj = PQb + (size_t)(b * NN + jn) * 192;
      p2[t] = bf2f(pqj[64 + o]);
      q2[t] = bf2f(pqj[128 + o]);
    }
    float m = q2[0];
    #pragma unroll
    for (int t = 1; t < NK; ++t) m = fmaxf(m, q2[t]);
    float s = 0.f, num = 0.f;
    #pragma unroll
    for (int t = 0; t < NK; ++t) {
      float e = __expf(q2[t] - m);
      s += e;
      num = fmaf(e, p1b + p2[t], num);
    }
    ot[p][o] = num / s;
  }
  __syncthreads();

  const int oo = tid >> 2, qq = tid & 3;
  float* og = out + (size_t)(b * NO + oo) * NN + n0 + qq * 16;
  #pragma unroll
  for (int i = 0; i < 4; ++i) {
    float4 v;
    v.x = ot[qq * 16 + i * 4 + 0][oo];
    v.y = ot[qq * 16 + i * 4 + 1][oo];
    v.z = ot[qq * 16 + i * 4 + 2][oo];
    v.w = ot[qq * 16 + i * 4 + 3][oo];
    *(float4*)&og[i * 4] = v;
  }
}

// ---------------------------------------------------------------------------
extern "C" void kernel_launch(void* const* d_in, const int* in_sizes, int n_in,
                              void* d_out, int out_size, void* d_ws, size_t ws_size,
                              hipStream_t stream)
{
  const float* x  = (const float*)d_in[0];
  const float* We = (const float*)d_in[1];
  const float* be = (const float*)d_in[2];
  const float* Wa = (const float*)d_in[3];
  float* out = (float*)d_out;

  // workspace: 26.8 MB (< proven 33.69 MB envelope)
  char* ws = (char*)d_ws;
  size_t off = 0;
  float* sq = (float*)(ws + off);                   off += (size_t)NB * NN * 4;         // 128 KB
  unsigned short* PQb = (unsigned short*)(ws + off); off += (size_t)NB * NN * 192 * 2;  // 12.6 MB
  float* XT = (float*)(ws + off);                   off += (size_t)NB * NN * NC * 4;    // 8 MB
  unsigned short* H = (unsigned short*)(ws + off);  off += (size_t)NB * NN * NC * 2;    // 4 MB
  unsigned short* cand = (unsigned short*)(ws + off);                                   // 2 MB
  int* nn = (int*)cand;   // exact per-row 64B overlay; written after reads (block-local)

  dim3 blk(256);
  proj_kernel<<<dim3(NB * (NN / TILE)), blk, 0, stream>>>(x, We, be, Wa, PQb, sq, XT, H);
  knn_kernel<<<dim3(NB * (NN / TILE) * NCHUNK), blk, 0, stream>>>(H, sq, cand);
  rescore_kernel<<<dim3(NB * NN / 8), blk, 0, stream>>>(XT, sq, cand, nn);
  out_kernel<<<dim3(NB * (NN / TILE)), blk, 0, stream>>>(PQb, nn, out);
}